// Round 4
// baseline (644.395 us; speedup 1.0000x reference)
//
#include <hip/hip_runtime.h>

typedef unsigned short u16;
typedef unsigned int u32;
typedef unsigned long long u64;
typedef __bf16 v8bf __attribute__((ext_vector_type(8)));
typedef _Float16 f16;
typedef _Float16 v8hf __attribute__((ext_vector_type(8)));
typedef float f32x4 __attribute__((ext_vector_type(4)));

#define BATCH 16384
#define IN_DIM 700
#define IN_PAD 704
#define H_ENC 2048
#define LATENT 512
#define H_DEC 2048
#define OUT_DIM 700
#define OUT_PAD 768
#define NUM_EMB 1024

// pre-scales keep split-hi (and nearly all split-lo) in fp16 normal range
#define SA 16.0f
#define SB 64.0f
#define INV_SASB 9.765625e-4f   // 2^-10 exact

__device__ __forceinline__ float b2f(u16 u) {
    u32 x = ((u32)u) << 16;
    return __uint_as_float(x);
}
__device__ __forceinline__ u16 f2b(float f) {  // round-to-nearest-even
    u32 x = __float_as_uint(f);
    u32 r = x + 0x7fffu + ((x >> 16) & 1u);
    return (u16)(r >> 16);
}
// unscaled residual split: v = hi + lo
__device__ __forceinline__ void splitf(float v, f16& hi, f16& lo) {
    hi = (f16)v;
    lo = (f16)(v - (float)hi);
}
// float -> monotone-orderable u32 (ascending)
__device__ __forceinline__ u32 f2ord(float f) {
    u32 u = __float_as_uint(f);
    return (u >> 31) ? ~u : (u | 0x80000000u);
}

// async global->LDS, 16B per lane; lds dest wave-uniform base (+lane*16 by HW)
__device__ __forceinline__ void gld16(const void* g, void* s) {
    __builtin_amdgcn_global_load_lds((const __attribute__((address_space(1))) void*)g,
                                     (__attribute__((address_space(3))) void*)s, 16, 0, 0);
}

// ---- LDS bank-conflict swizzle (row-pair XOR), verified R1: conflicts 1.15e7 -> 0 ----
//   write side: src col elems = ((lane&3) ^ ((lane>>3)&3)) * 8   (16-row periodic)
//   read  side: col elems     = ((lane>>4) ^ (((lane&15)>>1)&3)) * 8
// ---- R4: 256x256 tile, BK=32, 8 waves (2Mx4N, 128x64 out/wave) --------------------
// 2x arithmetic intensity per staged byte vs 128^2 (196 vs 97 FLOP/LDS-byte); loop
// skeleton = R3's verified counted-vmcnt dbuf; setprio(1) around MFMA clusters (T5).

// ---------------- conversion kernels ----------------

__global__ void split_x(const float* __restrict__ x, f16* __restrict__ xh, f16* __restrict__ xl) {
    int idx = blockIdx.x * 256 + threadIdx.x;
    if (idx >= BATCH * IN_PAD) return;
    int r = idx / IN_PAD, c = idx - r * IN_PAD;
    float v = (c < IN_DIM) ? x[(size_t)r * IN_DIM + c] * SA : 0.f;
    f16 hi, lo;
    splitf(v, hi, lo);
    xh[idx] = hi;
    xl[idx] = lo;
}

// W:[K][N] fp32 row-major -> Th/Tl:[N][Kp] f16 split of W*scale (zero padded); Tf optional raw fp32
__global__ void transpose_split(const float* __restrict__ W, f16* __restrict__ Th,
                                f16* __restrict__ Tl, float* __restrict__ Tf,
                                int K, int N, int Kp, float scale) {
    __shared__ float tile[32][33];
    int kb = blockIdx.x * 32, nb = blockIdx.y * 32;
    int tx = threadIdx.x, ty = threadIdx.y;
    for (int i = ty; i < 32; i += 8) {
        int k = kb + i, n = nb + tx;
        tile[i][tx] = (k < K && n < N) ? W[(size_t)k * N + n] : 0.f;
    }
    __syncthreads();
    for (int i = ty; i < 32; i += 8) {
        int n = nb + i, kk = kb + tx;
        if (n < N && kk < Kp) {
            float v = tile[tx][i];
            if (Tf) Tf[(size_t)n * Kp + kk] = v;
            f16 hi, lo;
            splitf(v * scale, hi, lo);
            Th[(size_t)n * Kp + kk] = hi;
            Tl[(size_t)n * Kp + kk] = lo;
        }
    }
}

// W:[K][N] fp32 -> WT:[Np][Kp] bf16 (zero padded) — decoder weights
__global__ void transpose_pad(const float* __restrict__ W, u16* __restrict__ WT,
                              int K, int N, int Kp, int Np) {
    __shared__ float tile[32][33];
    int kb = blockIdx.x * 32, nb = blockIdx.y * 32;
    int tx = threadIdx.x, ty = threadIdx.y;
    for (int i = ty; i < 32; i += 8) {
        int k = kb + i, n = nb + tx;
        tile[i][tx] = (k < K && n < N) ? W[(size_t)k * N + n] : 0.f;
    }
    __syncthreads();
    for (int i = ty; i < 32; i += 8) {
        int n = nb + i, k = kb + tx;
        if (n < Np && k < Kp) WT[(size_t)n * Kp + k] = f2b(tile[tx][i]);
    }
}

__global__ void enorm_k(const float* __restrict__ emb, float* __restrict__ enorm) {
    int n = blockIdx.x * 256 + threadIdx.x;
    if (n >= NUM_EMB) return;
    double s = 0.0;  // exact-grade |e_j|^2
    for (int k = 0; k < LATENT; ++k) {
        float v = emb[(size_t)k * NUM_EMB + n];
        s += (double)v * (double)v;
    }
    enorm[n] = (float)s;
}

// ---------------- fp16x2 GEMM, 128^2 tile (kept for MODE 2, N=512 grids) -------------
// MODE 2: store split(v*SA) to Oh/Ol (z)
template <int MODE>
__global__ __launch_bounds__(256) void gemm2(
    const f16* __restrict__ Ahg, const f16* __restrict__ Alg,
    const f16* __restrict__ Bhg, const f16* __restrict__ Blg,
    const float* __restrict__ bias,
    f16* __restrict__ Oh, f16* __restrict__ Ol, u64* __restrict__ Part,
    int N, int K) {
    // double-buffered: [2][128][32] each
    __shared__ f16 Ah[2 * 4096];
    __shared__ f16 Al[2 * 4096];
    __shared__ f16 Bh[2 * 4096];
    __shared__ f16 Bl[2 * 4096];
    const int w = threadIdx.x >> 6;
    const int lane = threadIdx.x & 63;
    const int bm = blockIdx.y * 128;
    const int bn = blockIdx.x * 128;

    const int srow = w * 32 + (lane >> 2);
    const int scol = ((lane & 3) ^ ((lane >> 3) & 3)) * 8;
    const f16* AhG = Ahg + (size_t)(bm + srow) * K + scol;
    const f16* AlG = Alg + (size_t)(bm + srow) * K + scol;
    const f16* BhG = Bhg + (size_t)(bn + srow) * K + scol;
    const f16* BlG = Blg + (size_t)(bn + srow) * K + scol;
    f16* AhW = &Ah[(w * 32) * 32];
    f16* AlW = &Al[(w * 32) * 32];
    f16* BhW = &Bh[(w * 32) * 32];
    f16* BlW = &Bl[(w * 32) * 32];

    const int mBase = (w >> 1) * 64;
    const int nBase = (w & 1) * 64;
    const int co = ((lane >> 4) ^ (((lane & 15) >> 1) & 3)) * 8;

    f32x4 acc[4][4];
    const f32x4 z4 = {0.f, 0.f, 0.f, 0.f};
#pragma unroll
    for (int a = 0; a < 4; ++a)
#pragma unroll
        for (int b = 0; b < 4; ++b) acc[a][b] = z4;

    auto STAGE = [&](int k0, int b) {
        const int o = b << 12;  // 4096 f16 per buffer
        gld16(AhG + k0, AhW + o);
        gld16(AhG + k0 + (size_t)16 * K, AhW + o + 16 * 32);
        gld16(AlG + k0, AlW + o);
        gld16(AlG + k0 + (size_t)16 * K, AlW + o + 16 * 32);
        gld16(BhG + k0, BhW + o);
        gld16(BhG + k0 + (size_t)16 * K, BhW + o + 16 * 32);
        gld16(BlG + k0, BlW + o);
        gld16(BlG + k0 + (size_t)16 * K, BlW + o + 16 * 32);
    };
    auto COMPUTE = [&](int b) {
        const int o = b << 12;
        v8hf ah[4], al[4], bh[4], bl[4];
#pragma unroll
        for (int t = 0; t < 4; ++t) {
            const int ro = (t * 16 + (lane & 15)) * 32 + co;
            ah[t] = *(const v8hf*)&Ah[o + mBase * 32 + ro];
            al[t] = *(const v8hf*)&Al[o + mBase * 32 + ro];
            bh[t] = *(const v8hf*)&Bh[o + nBase * 32 + ro];
            bl[t] = *(const v8hf*)&Bl[o + nBase * 32 + ro];
        }
        // cross terms first (small), big hh term last — preserves their low bits
#pragma unroll
        for (int tm = 0; tm < 4; ++tm)
#pragma unroll
            for (int tn = 0; tn < 4; ++tn)
                acc[tm][tn] = __builtin_amdgcn_mfma_f32_16x16x32_f16(ah[tm], bl[tn], acc[tm][tn], 0, 0, 0);
#pragma unroll
        for (int tm = 0; tm < 4; ++tm)
#pragma unroll
            for (int tn = 0; tn < 4; ++tn)
                acc[tm][tn] = __builtin_amdgcn_mfma_f32_16x16x32_f16(al[tm], bh[tn], acc[tm][tn], 0, 0, 0);
#pragma unroll
        for (int tm = 0; tm < 4; ++tm)
#pragma unroll
            for (int tn = 0; tn < 4; ++tn)
                acc[tm][tn] = __builtin_amdgcn_mfma_f32_16x16x32_f16(ah[tm], bh[tn], acc[tm][tn], 0, 0, 0);
    };

    const int nt = K >> 5;
    STAGE(0, 0);
    int cur = 0;
    for (int t = 0; t < nt - 1; ++t) {
        STAGE((t + 1) << 5, cur ^ 1);
        asm volatile("s_waitcnt vmcnt(8)" ::: "memory");
        __builtin_amdgcn_s_barrier();
        COMPUTE(cur);
        asm volatile("s_waitcnt lgkmcnt(0)" ::: "memory");
        __builtin_amdgcn_s_barrier();
        cur ^= 1;
    }
    asm volatile("s_waitcnt vmcnt(0)" ::: "memory");
    __builtin_amdgcn_s_barrier();
    COMPUTE(cur);

    // C/D frag layout col=lane&15, row=(lane>>4)*4+r
#pragma unroll
    for (int tm = 0; tm < 4; ++tm) {
        const int r0 = bm + mBase + tm * 16 + (lane >> 4) * 4;
#pragma unroll
        for (int tn = 0; tn < 4; ++tn) {
            const int c = bn + nBase + tn * 16 + (lane & 15);
            const float bvv = bias[c];
#pragma unroll
            for (int r = 0; r < 4; ++r) {
                float v = acc[tm][tn][r] * INV_SASB + bvv;
                if (MODE == 1) v = (v >= 0.f) ? v : 0.2f * v;
                const size_t o = (size_t)(r0 + r) * N + c;
                f16 hi, lo;
                splitf(v * SA, hi, lo);
                Oh[o] = hi;
                Ol[o] = lo;
            }
        }
    }
}

// ---------------- fp16x2 GEMM, 256^2 tile, 8 waves (MODE 1 and 3) --------------------
// wave w: wr=w>>2 (M half), wc=w&3 (N quarter); wave out 128x64; frag tm 0..7, tn 0..3
// MODE 3 Part slot: blockIdx.x*4 + wc (N=1024 -> 4 blocks x 4 col-waves = 16 slots).
template <int MODE>
__global__ __launch_bounds__(512) void gemm2w(
    const f16* __restrict__ Ahg, const f16* __restrict__ Alg,
    const f16* __restrict__ Bhg, const f16* __restrict__ Blg,
    const float* __restrict__ bias,
    f16* __restrict__ Oh, f16* __restrict__ Ol, u64* __restrict__ Part,
    int N, int K) {
    // [2][256][32] each = 32 KB; 4 matrices = 128 KB (gfx950 WG limit 160 KB)
    __shared__ f16 Ah[2 * 8192];
    __shared__ f16 Al[2 * 8192];
    __shared__ f16 Bh[2 * 8192];
    __shared__ f16 Bl[2 * 8192];
    const int w = threadIdx.x >> 6;
    const int lane = threadIdx.x & 63;
    const int bm = blockIdx.y * 256;
    const int bn = blockIdx.x * 256;

    const int srow = w * 32 + (lane >> 2);  // 0..255: wave w stages rows [w*32, w*32+32)
    const int scol = ((lane & 3) ^ ((lane >> 3) & 3)) * 8;
    const f16* AhG = Ahg + (size_t)(bm + srow) * K + scol;
    const f16* AlG = Alg + (size_t)(bm + srow) * K + scol;
    const f16* BhG = Bhg + (size_t)(bn + srow) * K + scol;
    const f16* BlG = Blg + (size_t)(bn + srow) * K + scol;
    f16* AhW = &Ah[(w * 32) * 32];
    f16* AlW = &Al[(w * 32) * 32];
    f16* BhW = &Bh[(w * 32) * 32];
    f16* BlW = &Bl[(w * 32) * 32];

    const int wc = w & 3;
    const int mBase = (w >> 2) * 128;
    const int nBase = wc * 64;
    const int co = ((lane >> 4) ^ (((lane & 15) >> 1) & 3)) * 8;

    f32x4 acc[8][4];
    const f32x4 z4 = {0.f, 0.f, 0.f, 0.f};
#pragma unroll
    for (int a = 0; a < 8; ++a)
#pragma unroll
        for (int b = 0; b < 4; ++b) acc[a][b] = z4;

    auto STAGE = [&](int k0, int b) {
        const int o = b << 13;  // 8192 f16 per buffer
        gld16(AhG + k0, AhW + o);
        gld16(AhG + k0 + (size_t)16 * K, AhW + o + 512);
        gld16(AlG + k0, AlW + o);
        gld16(AlG + k0 + (size_t)16 * K, AlW + o + 512);
        gld16(BhG + k0, BhW + o);
        gld16(BhG + k0 + (size_t)16 * K, BhW + o + 512);
        gld16(BlG + k0, BlW + o);
        gld16(BlG + k0 + (size_t)16 * K, BlW + o + 512);
    };
    auto COMPUTE = [&](int b) {
        const int o = b << 13;
        v8hf bh4[4], bl4[4];
#pragma unroll
        for (int tn = 0; tn < 4; ++tn) {
            const int ro = o + (nBase + tn * 16 + (lane & 15)) * 32 + co;
            bh4[tn] = *(const v8hf*)&Bh[ro];
            bl4[tn] = *(const v8hf*)&Bl[ro];
        }
        // two halves of 4 A-frag rows each limit live A registers
#pragma unroll
        for (int h = 0; h < 2; ++h) {
            v8hf ah4[4], al4[4];
#pragma unroll
            for (int j = 0; j < 4; ++j) {
                const int ro = o + (mBase + (h * 4 + j) * 16 + (lane & 15)) * 32 + co;
                ah4[j] = *(const v8hf*)&Ah[ro];
                al4[j] = *(const v8hf*)&Al[ro];
            }
            __builtin_amdgcn_s_setprio(1);
            // per-acc order: ah*bl, al*bh, ah*bh (cross first, big hh last)
#pragma unroll
            for (int j = 0; j < 4; ++j)
#pragma unroll
                for (int tn = 0; tn < 4; ++tn)
                    acc[h * 4 + j][tn] = __builtin_amdgcn_mfma_f32_16x16x32_f16(ah4[j], bl4[tn], acc[h * 4 + j][tn], 0, 0, 0);
#pragma unroll
            for (int j = 0; j < 4; ++j)
#pragma unroll
                for (int tn = 0; tn < 4; ++tn)
                    acc[h * 4 + j][tn] = __builtin_amdgcn_mfma_f32_16x16x32_f16(al4[j], bh4[tn], acc[h * 4 + j][tn], 0, 0, 0);
#pragma unroll
            for (int j = 0; j < 4; ++j)
#pragma unroll
                for (int tn = 0; tn < 4; ++tn)
                    acc[h * 4 + j][tn] = __builtin_amdgcn_mfma_f32_16x16x32_f16(ah4[j], bh4[tn], acc[h * 4 + j][tn], 0, 0, 0);
            __builtin_amdgcn_s_setprio(0);
        }
    };

    const int nt = K >> 5;
    STAGE(0, 0);
    int cur = 0;
    for (int t = 0; t < nt - 1; ++t) {
        STAGE((t + 1) << 5, cur ^ 1);
        asm volatile("s_waitcnt vmcnt(8)" ::: "memory");
        __builtin_amdgcn_s_barrier();
        COMPUTE(cur);
        asm volatile("s_waitcnt lgkmcnt(0)" ::: "memory");
        __builtin_amdgcn_s_barrier();
        cur ^= 1;
    }
    asm volatile("s_waitcnt vmcnt(0)" ::: "memory");
    __builtin_amdgcn_s_barrier();
    COMPUTE(cur);

    if (MODE == 3) {
        // per-row partial argmin over this wave's 64 cols
#pragma unroll
        for (int tm = 0; tm < 8; ++tm) {
#pragma unroll
            for (int r = 0; r < 4; ++r) {
                u64 key = ~0ull;
#pragma unroll
                for (int tn = 0; tn < 4; ++tn) {
                    const int c = bn + nBase + tn * 16 + (lane & 15);
                    float score = bias[c] - 2.0f * (acc[tm][tn][r] * INV_SASB);
                    u64 k = ((u64)f2ord(score) << 10) | (u32)c;
                    key = (k < key) ? k : key;
                }
#pragma unroll
                for (int m = 1; m < 16; m <<= 1) {
                    u64 o = __shfl_xor((unsigned long long)key, m);
                    key = (o < key) ? o : key;
                }
                if ((lane & 15) == 0) {
                    const int row = bm + mBase + tm * 16 + (lane >> 4) * 4 + r;
                    Part[(size_t)row * 16 + blockIdx.x * 4 + wc] = key;
                }
            }
        }
        return;
    }

    // C/D frag layout col=lane&15, row=(lane>>4)*4+r
#pragma unroll
    for (int tm = 0; tm < 8; ++tm) {
        const int r0 = bm + mBase + tm * 16 + (lane >> 4) * 4;
#pragma unroll
        for (int tn = 0; tn < 4; ++tn) {
            const int c = bn + nBase + tn * 16 + (lane & 15);
            const float bvv = bias[c];
#pragma unroll
            for (int r = 0; r < 4; ++r) {
                float v = acc[tm][tn][r] * INV_SASB + bvv;
                if (MODE == 1) v = (v >= 0.f) ? v : 0.2f * v;
                const size_t o = (size_t)(r0 + r) * N + c;
                f16 hi, lo;
                splitf(v * SA, hi, lo);
                Oh[o] = hi;
                Ol[o] = lo;
            }
        }
    }
}

// ---------------- bf16 GEMM (decoder), 256^2 tile, 8 waves ---------------------------
// MODE 0: f32 store, +bias, predicated c<Nreal (recon). MODE 1: bf16 store, +bias, leaky.
template <int MODE>
__global__ __launch_bounds__(512) void gemm_btw(
    const u16* __restrict__ A, const u16* __restrict__ B,
    const float* __restrict__ bias, void* __restrict__ Cout,
    int N, int K, int ldc, int Nreal) {
    __shared__ u16 As[2 * 8192];
    __shared__ u16 Bs[2 * 8192];
    const int w = threadIdx.x >> 6;
    const int lane = threadIdx.x & 63;
    const int bm = blockIdx.y * 256;
    const int bn = blockIdx.x * 256;

    const int srow = w * 32 + (lane >> 2);
    const int scol = ((lane & 3) ^ ((lane >> 3) & 3)) * 8;
    const u16* Ag = A + (size_t)(bm + srow) * K + scol;
    const u16* Bg = B + (size_t)(bn + srow) * K + scol;
    u16* AsW = &As[(w * 32) * 32];
    u16* BsW = &Bs[(w * 32) * 32];

    const int mBase = (w >> 2) * 128;
    const int nBase = (w & 3) * 64;
    const int co = ((lane >> 4) ^ (((lane & 15) >> 1) & 3)) * 8;

    f32x4 acc[8][4];
    const f32x4 z4 = {0.f, 0.f, 0.f, 0.f};
#pragma unroll
    for (int a = 0; a < 8; ++a)
#pragma unroll
        for (int b = 0; b < 4; ++b) acc[a][b] = z4;

    auto STAGE = [&](int k0, int b) {
        const int o = b << 13;
        gld16(Ag + k0, AsW + o);
        gld16(Ag + k0 + (size_t)16 * K, AsW + o + 512);
        gld16(Bg + k0, BsW + o);
        gld16(Bg + k0 + (size_t)16 * K, BsW + o + 512);
    };
    auto COMPUTE = [&](int b) {
        const int o = b << 13;
        v8bf bv[4];
#pragma unroll
        for (int tn = 0; tn < 4; ++tn)
            bv[tn] = *(const v8bf*)&Bs[o + (nBase + tn * 16 + (lane & 15)) * 32 + co];
#pragma unroll
        for (int h = 0; h < 2; ++h) {
            v8bf af[4];
#pragma unroll
            for (int j = 0; j < 4; ++j)
                af[j] = *(const v8bf*)&As[o + (mBase + (h * 4 + j) * 16 + (lane & 15)) * 32 + co];
            __builtin_amdgcn_s_setprio(1);
#pragma unroll
            for (int j = 0; j < 4; ++j)
#pragma unroll
                for (int tn = 0; tn < 4; ++tn)
                    acc[h * 4 + j][tn] = __builtin_amdgcn_mfma_f32_16x16x32_bf16(af[j], bv[tn], acc[h * 4 + j][tn], 0, 0, 0);
            __builtin_amdgcn_s_setprio(0);
        }
    };

    const int nt = K >> 5;
    STAGE(0, 0);
    int cur = 0;
    for (int t = 0; t < nt - 1; ++t) {
        STAGE((t + 1) << 5, cur ^ 1);
        asm volatile("s_waitcnt vmcnt(4)" ::: "memory");
        __builtin_amdgcn_s_barrier();
        COMPUTE(cur);
        asm volatile("s_waitcnt lgkmcnt(0)" ::: "memory");
        __builtin_amdgcn_s_barrier();
        cur ^= 1;
    }
    asm volatile("s_waitcnt vmcnt(0)" ::: "memory");
    __builtin_amdgcn_s_barrier();
    COMPUTE(cur);

#pragma unroll
    for (int tm = 0; tm < 8; ++tm) {
        const int r0 = bm + mBase + tm * 16 + (lane >> 4) * 4;
#pragma unroll
        for (int tn = 0; tn < 4; ++tn) {
            const int c = bn + nBase + tn * 16 + (lane & 15);
            if (MODE == 0 && c >= Nreal) continue;
            const float bvv = bias[c];
#pragma unroll
            for (int r = 0; r < 4; ++r) {
                float v = acc[tm][tn][r] + bvv;
                if (MODE == 1) v = (v >= 0.f) ? v : 0.2f * v;
                const size_t o = (size_t)(r0 + r) * ldc + c;
                if (MODE == 0)
                    ((float*)Cout)[o] = v;
                else
                    ((u16*)Cout)[o] = f2b(v);
            }
        }
    }
}

// ---------------- VQ finish: reduce 16 partials/row, gather, loss partials; wave per row --------
__global__ __launch_bounds__(256) void vq2(
    const u64* __restrict__ Part, const float* __restrict__ embF,
    const f16* __restrict__ zh, const f16* __restrict__ zl,
    u16* __restrict__ qb, float* __restrict__ lossPart) {
    __shared__ float ls[4];
    const int lane = threadIdx.x & 63;
    const int wv = threadIdx.x >> 6;
    const int row = blockIdx.x * 4 + wv;

    u64 key = (lane < 16) ? Part[(size_t)row * 16 + lane] : ~0ull;
#pragma unroll
    for (int m = 1; m < 16; m <<= 1) {
        u64 o = __shfl_xor((unsigned long long)key, m);
        key = (o < key) ? o : key;
    }
    const int bidx = (int)(__shfl((unsigned long long)key, 0) & 1023ull);

    // gather fp32 codebook row (lane covers 8 floats), bf16-ify for decoder, fp32 loss
    const float4 q0 = ((const float4*)(embF + (size_t)bidx * LATENT))[2 * lane];
    const float4 q1 = ((const float4*)(embF + (size_t)bidx * LATENT))[2 * lane + 1];
    float qf[8] = {q0.x, q0.y, q0.z, q0.w, q1.x, q1.y, q1.z, q1.w};
    u16 qpack[8];
#pragma unroll
    for (int t = 0; t < 8; ++t) qpack[t] = f2b(qf[t]);
    *(uint4*)(qb + (size_t)row * LATENT + lane * 8) = *(const uint4*)qpack;

    v8hf zh8 = *(const v8hf*)(zh + (size_t)row * LATENT + lane * 8);
    v8hf zl8 = *(const v8hf*)(zl + (size_t)row * LATENT + lane * 8);
    float s = 0.f;
#pragma unroll
    for (int t = 0; t < 8; ++t) {
        float z = ((float)zh8[t] + (float)zl8[t]) * (1.0f / SA);
        float df = qf[t] - z;
        s += df * df;
    }
    for (int off = 32; off > 0; off >>= 1) s += __shfl_down(s, off);
    if (lane == 0) ls[wv] = s;
    __syncthreads();
    if (threadIdx.x == 0) lossPart[blockIdx.x] = ls[0] + ls[1] + ls[2] + ls[3];
}

__global__ __launch_bounds__(256) void reduce_loss(const float* __restrict__ lossPart,
                                                   float* __restrict__ outLoss) {
    __shared__ float ls[4];
    const int lane = threadIdx.x & 63;
    const int wv = threadIdx.x >> 6;
    float s = 0.f;
    for (int i = threadIdx.x; i < BATCH / 4; i += 256) s += lossPart[i];
    for (int off = 32; off > 0; off >>= 1) s += __shfl_down(s, off);
    if (lane == 0) ls[wv] = s;
    __syncthreads();
    if (threadIdx.x == 0)
        outLoss[0] = 1.25f * (ls[0] + ls[1] + ls[2] + ls[3]) / (float)(BATCH * LATENT);
}

// ---------------- launch ----------------
extern "C" void kernel_launch(void* const* d_in, const int* in_sizes, int n_in,
                              void* d_out, int out_size, void* d_ws, size_t ws_size,
                              hipStream_t stream) {
    const float* x = (const float*)d_in[0];
    const float* W1 = (const float*)d_in[1];
    const float* b1 = (const float*)d_in[2];
    const float* W2 = (const float*)d_in[3];
    const float* b2 = (const float*)d_in[4];
    const float* emb = (const float*)d_in[5];
    const float* W3 = (const float*)d_in[6];
    const float* b3 = (const float*)d_in[7];
    const float* W4 = (const float*)d_in[8];
    const float* b4 = (const float*)d_in[9];
    float* out = (float*)d_out;

    char* ws = (char*)d_ws;
    size_t off = 0;
    auto alloc = [&](size_t bytes) {
        void* p = ws + off;
        off += (bytes + 255) & ~(size_t)255;
        return p;
    };
    // A: h_hi (f16 16384x2048)
    char* A = (char*)alloc((size_t)BATCH * H_ENC * 2);
    // B: h_lo (f16) -> h2 (bf16 16384x2048)
    char* Breg = (char*)alloc((size_t)BATCH * H_ENC * 2);
    // C: xh+xl (f16 16384x704 each) -> zh+zl (f16 16384x512 each)
    char* C = (char*)alloc((size_t)BATCH * IN_PAD * 2 * 2);
    u16* qb = (u16*)alloc((size_t)BATCH * LATENT * 2);
    u64* Part = (u64*)alloc((size_t)BATCH * 16 * 8);
    float* lossPart = (float*)alloc((BATCH / 4) * 4);
    f16* W1Th = (f16*)alloc((size_t)H_ENC * IN_PAD * 2);
    f16* W1Tl = (f16*)alloc((size_t)H_ENC * IN_PAD * 2);
    f16* W2Th = (f16*)alloc((size_t)LATENT * H_ENC * 2);
    f16* W2Tl = (f16*)alloc((size_t)LATENT * H_ENC * 2);
    f16* eTh = (f16*)alloc((size_t)NUM_EMB * LATENT * 2);
    f16* eTl = (f16*)alloc((size_t)NUM_EMB * LATENT * 2);
    float* eTf = (float*)alloc((size_t)NUM_EMB * LATENT * 4);
    u16* W3T = (u16*)alloc((size_t)H_DEC * LATENT * 2);
    u16* W4T = (u16*)alloc((size_t)OUT_PAD * H_DEC * 2);
    float* enorm = (float*)alloc(NUM_EMB * 4);

    f16* h_hi = (f16*)A;
    f16* h_lo = (f16*)Breg;
    u16* h2 = (u16*)Breg;
    f16* xh = (f16*)C;
    f16* xl = xh + (size_t)BATCH * IN_PAD;
    f16* zh = (f16*)C;
    f16* zl = zh + (size_t)BATCH * LATENT;

    // conversions
    split_x<<<(BATCH * IN_PAD + 255) / 256, 256, 0, stream>>>(x, xh, xl);
    transpose_split<<<dim3(IN_PAD / 32, H_ENC / 32), dim3(32, 8), 0, stream>>>(W1, W1Th, W1Tl, nullptr, IN_DIM, H_ENC, IN_PAD, SB);
    transpose_split<<<dim3(H_ENC / 32, LATENT / 32), dim3(32, 8), 0, stream>>>(W2, W2Th, W2Tl, nullptr, H_ENC, LATENT, H_ENC, SB);
    transpose_split<<<dim3(LATENT / 32, NUM_EMB / 32), dim3(32, 8), 0, stream>>>(emb, eTh, eTl, eTf, LATENT, NUM_EMB, LATENT, SB);
    transpose_pad<<<dim3(LATENT / 32, H_DEC / 32), dim3(32, 8), 0, stream>>>(W3, W3T, LATENT, H_DEC, LATENT, H_DEC);
    transpose_pad<<<dim3(H_DEC / 32, OUT_PAD / 32), dim3(32, 8), 0, stream>>>(W4, W4T, H_DEC, OUT_DIM, H_DEC, OUT_PAD);
    enorm_k<<<(NUM_EMB + 255) / 256, 256, 0, stream>>>(emb, enorm);

    // encoder layer 1: 256^2 tile (N=2048 -> 8x64 = 512 WGs)
    gemm2w<1><<<dim3(H_ENC / 256, BATCH / 256), 512, 0, stream>>>(xh, xl, W1Th, W1Tl, b1, h_hi, h_lo, nullptr, H_ENC, IN_PAD);
    // encoder layer 2: 128^2 tile (N=512 would underfill at 256^2)
    gemm2<2><<<dim3(LATENT / 128, BATCH / 128), 256, 0, stream>>>(h_hi, h_lo, W2Th, W2Tl, b2, zh, zl, nullptr, LATENT, H_ENC);
    // distance pass: 256^2 tile (N=1024 -> 4x64 = 256 WGs, exact fill)
    gemm2w<3><<<dim3(NUM_EMB / 256, BATCH / 256), 512, 0, stream>>>(zh, zl, eTh, eTl, enorm, nullptr, nullptr, Part, NUM_EMB, LATENT);
    // VQ finish (no atomics)
    vq2<<<BATCH / 4, 256, 0, stream>>>(Part, eTf, zh, zl, qb, lossPart);
    // decoder (bf16, 256^2)
    gemm_btw<1><<<dim3(H_DEC / 256, BATCH / 256), 512, 0, stream>>>(qb, W3T, b3, h2, H_DEC, LATENT, H_DEC, H_DEC);
    gemm_btw<0><<<dim3(OUT_PAD / 256, BATCH / 256), 512, 0, stream>>>(h2, W4T, b4, out, OUT_PAD, H_DEC, OUT_DIM, OUT_DIM);
    reduce_loss<<<1, 256, 0, stream>>>(lossPart, out + (size_t)BATCH * OUT_DIM);

    (void)in_sizes; (void)n_in; (void)out_size; (void)ws_size;
}

// Round 5
// 590.967 us; speedup vs baseline: 1.0904x; 1.0904x over previous
//
#include <hip/hip_runtime.h>

typedef unsigned short u16;
typedef unsigned int u32;
typedef unsigned long long u64;
typedef __bf16 v8bf __attribute__((ext_vector_type(8)));
typedef _Float16 f16;
typedef _Float16 v8hf __attribute__((ext_vector_type(8)));
typedef float f32x4 __attribute__((ext_vector_type(4)));

#define BATCH 16384
#define IN_DIM 700
#define IN_PAD 704
#define H_ENC 2048
#define LATENT 512
#define H_DEC 2048
#define OUT_DIM 700
#define OUT_PAD 768
#define NUM_EMB 1024

// pre-scales keep split-hi (and nearly all split-lo) in fp16 normal range
#define SA 16.0f
#define SB 64.0f
#define INV_SASB 9.765625e-4f   // 2^-10 exact

__device__ __forceinline__ u16 f2b(float f) {  // round-to-nearest-even
    u32 x = __float_as_uint(f);
    u32 r = x + 0x7fffu + ((x >> 16) & 1u);
    return (u16)(r >> 16);
}
// unscaled residual split: v = hi + lo
__device__ __forceinline__ void splitf(float v, f16& hi, f16& lo) {
    hi = (f16)v;
    lo = (f16)(v - (float)hi);
}
// float -> monotone-orderable u32 (ascending)
__device__ __forceinline__ u32 f2ord(float f) {
    u32 u = __float_as_uint(f);
    return (u >> 31) ? ~u : (u | 0x80000000u);
}

// async global->LDS, 16B per lane; lds dest wave-uniform base (+lane*16 by HW)
__device__ __forceinline__ void gld16(const void* g, void* s) {
    __builtin_amdgcn_global_load_lds((const __attribute__((address_space(1))) void*)g,
                                     (__attribute__((address_space(3))) void*)s, 16, 0, 0);
}

// T1: bijective XCD-chunk swizzle (requires nwg % 8 == 0, true for all our grids).
// Physical consecutive ids round-robin XCDs; remap so each XCD owns a contiguous
// chunk of logical ids -> blocks sharing an A-panel land on the same XCD's L2.
__device__ __forceinline__ void xcd_swz(int& bx, int& by) {
    const u32 nx = gridDim.x;
    const u32 p = blockIdx.y * nx + blockIdx.x;
    const u32 chunk = (nx * gridDim.y) >> 3;
    const u32 s = (p & 7u) * chunk + (p >> 3);
    bx = (int)(s % nx);
    by = (int)(s / nx);
}

// ---- LDS bank-conflict swizzle (row-pair XOR), verified R1: conflicts 1.15e7 -> 0 ----
//   write side: src col elems = ((lane&3) ^ ((lane>>3)&3)) * 8   (16-row periodic)
//   read  side: col elems     = ((lane>>4) ^ (((lane&15)>>1)&3)) * 8
// ---- K-loop: dbuf + counted vmcnt (R3-verified skeleton) ---------------------------

// ---------------- merged prep kernel (was 7 dispatches) ----------------
// block ranges: [0,45056) split_x | [45056,46464) ts W1 | [46464,47488) ts W2
// [47488,48000) ts emb | [48000,49024) tp W3 | [49024,50560) tp W4 | [50560,50564) enorm
__global__ __launch_bounds__(256) void prep(
    const float* __restrict__ x, const float* __restrict__ W1,
    const float* __restrict__ W2, const float* __restrict__ emb,
    const float* __restrict__ W3, const float* __restrict__ W4,
    f16* __restrict__ xh, f16* __restrict__ xl,
    f16* __restrict__ W1Th, f16* __restrict__ W1Tl,
    f16* __restrict__ W2Th, f16* __restrict__ W2Tl,
    f16* __restrict__ eTh, f16* __restrict__ eTl, float* __restrict__ eTf,
    u16* __restrict__ W3T, u16* __restrict__ W4T, float* __restrict__ enorm) {
    __shared__ float tile[32][33];
    const int b = blockIdx.x;
    const int t = threadIdx.x;

    if (b < 45056) {  // split_x: BATCH*IN_PAD = 45056*256 exactly
        const int idx = b * 256 + t;
        const int r = idx / IN_PAD, c = idx - r * IN_PAD;
        float v = (c < IN_DIM) ? x[(size_t)r * IN_DIM + c] * SA : 0.f;
        f16 hi, lo;
        splitf(v, hi, lo);
        xh[idx] = hi;
        xl[idx] = lo;
        return;
    }
    const int tx = t & 31, ty = t >> 5;

    auto ts = [&](const float* W, f16* Th, f16* Tl, float* Tf, int K, int N, int Kp,
                  float scale, int bx, int by) {
        const int kb = bx * 32, nb = by * 32;
        for (int i = ty; i < 32; i += 8) {
            int k = kb + i, n = nb + tx;
            tile[i][tx] = (k < K && n < N) ? W[(size_t)k * N + n] : 0.f;
        }
        __syncthreads();
        for (int i = ty; i < 32; i += 8) {
            int n = nb + i, kk = kb + tx;
            if (n < N && kk < Kp) {
                float v = tile[tx][i];
                if (Tf) Tf[(size_t)n * Kp + kk] = v;
                f16 hi, lo;
                splitf(v * scale, hi, lo);
                Th[(size_t)n * Kp + kk] = hi;
                Tl[(size_t)n * Kp + kk] = lo;
            }
        }
    };
    auto tp = [&](const float* W, u16* WT, int K, int N, int Kp, int Np, int bx, int by) {
        const int kb = bx * 32, nb = by * 32;
        for (int i = ty; i < 32; i += 8) {
            int k = kb + i, n = nb + tx;
            tile[i][tx] = (k < K && n < N) ? W[(size_t)k * N + n] : 0.f;
        }
        __syncthreads();
        for (int i = ty; i < 32; i += 8) {
            int n = nb + i, k = kb + tx;
            if (n < Np && k < Kp) WT[(size_t)n * Kp + k] = f2b(tile[tx][i]);
        }
    };

    if (b < 46464) {  // W1: grid was (22,64)
        const int i = b - 45056;
        ts(W1, W1Th, W1Tl, nullptr, IN_DIM, H_ENC, IN_PAD, SB, i % 22, i / 22);
    } else if (b < 47488) {  // W2: grid was (64,16)
        const int i = b - 46464;
        ts(W2, W2Th, W2Tl, nullptr, H_ENC, LATENT, H_ENC, SB, i % 64, i / 64);
    } else if (b < 48000) {  // emb: grid was (16,32)
        const int i = b - 47488;
        ts(emb, eTh, eTl, eTf, LATENT, NUM_EMB, LATENT, SB, i % 16, i / 16);
    } else if (b < 49024) {  // W3: grid was (16,64)
        const int i = b - 48000;
        tp(W3, W3T, LATENT, H_DEC, LATENT, H_DEC, i % 16, i / 16);
    } else if (b < 50560) {  // W4: grid was (64,24)
        const int i = b - 49024;
        tp(W4, W4T, H_DEC, OUT_DIM, H_DEC, OUT_PAD, i % 64, i / 64);
    } else {  // enorm: 4 blocks
        const int n = (b - 50560) * 256 + t;
        if (n < NUM_EMB) {
            double s = 0.0;
            for (int k = 0; k < LATENT; ++k) {
                float v = emb[(size_t)k * NUM_EMB + n];
                s += (double)v * (double)v;
            }
            enorm[n] = (float)s;
        }
    }
}

// ---------------- fp16x2 GEMM, 128^2 tile (MODE 2: z store; MODE 3: VQ argmin) -------
template <int MODE>
__global__ __launch_bounds__(256) void gemm2(
    const f16* __restrict__ Ahg, const f16* __restrict__ Alg,
    const f16* __restrict__ Bhg, const f16* __restrict__ Blg,
    const float* __restrict__ bias,
    f16* __restrict__ Oh, f16* __restrict__ Ol, u64* __restrict__ Part,
    int N, int K) {
    __shared__ f16 Ah[2 * 4096];
    __shared__ f16 Al[2 * 4096];
    __shared__ f16 Bh[2 * 4096];
    __shared__ f16 Bl[2 * 4096];
    const int w = threadIdx.x >> 6;
    const int lane = threadIdx.x & 63;
    int bx, by;
    xcd_swz(bx, by);
    const int bm = by * 128;
    const int bn = bx * 128;

    const int srow = w * 32 + (lane >> 2);
    const int scol = ((lane & 3) ^ ((lane >> 3) & 3)) * 8;
    const f16* AhG = Ahg + (size_t)(bm + srow) * K + scol;
    const f16* AlG = Alg + (size_t)(bm + srow) * K + scol;
    const f16* BhG = Bhg + (size_t)(bn + srow) * K + scol;
    const f16* BlG = Blg + (size_t)(bn + srow) * K + scol;
    f16* AhW = &Ah[(w * 32) * 32];
    f16* AlW = &Al[(w * 32) * 32];
    f16* BhW = &Bh[(w * 32) * 32];
    f16* BlW = &Bl[(w * 32) * 32];

    const int mBase = (w >> 1) * 64;
    const int nBase = (w & 1) * 64;
    const int co = ((lane >> 4) ^ (((lane & 15) >> 1) & 3)) * 8;

    f32x4 acc[4][4];
    const f32x4 z4 = {0.f, 0.f, 0.f, 0.f};
#pragma unroll
    for (int a = 0; a < 4; ++a)
#pragma unroll
        for (int b = 0; b < 4; ++b) acc[a][b] = z4;

    auto STAGE = [&](int k0, int b) {
        const int o = b << 12;
        gld16(AhG + k0, AhW + o);
        gld16(AhG + k0 + (size_t)16 * K, AhW + o + 16 * 32);
        gld16(AlG + k0, AlW + o);
        gld16(AlG + k0 + (size_t)16 * K, AlW + o + 16 * 32);
        gld16(BhG + k0, BhW + o);
        gld16(BhG + k0 + (size_t)16 * K, BhW + o + 16 * 32);
        gld16(BlG + k0, BlW + o);
        gld16(BlG + k0 + (size_t)16 * K, BlW + o + 16 * 32);
    };
    auto COMPUTE = [&](int b) {
        const int o = b << 12;
        v8hf ah[4], al[4], bh[4], bl[4];
#pragma unroll
        for (int t = 0; t < 4; ++t) {
            const int ro = (t * 16 + (lane & 15)) * 32 + co;
            ah[t] = *(const v8hf*)&Ah[o + mBase * 32 + ro];
            al[t] = *(const v8hf*)&Al[o + mBase * 32 + ro];
            bh[t] = *(const v8hf*)&Bh[o + nBase * 32 + ro];
            bl[t] = *(const v8hf*)&Bl[o + nBase * 32 + ro];
        }
        // cross terms first (small), big hh term last — preserves their low bits
#pragma unroll
        for (int tm = 0; tm < 4; ++tm)
#pragma unroll
            for (int tn = 0; tn < 4; ++tn)
                acc[tm][tn] = __builtin_amdgcn_mfma_f32_16x16x32_f16(ah[tm], bl[tn], acc[tm][tn], 0, 0, 0);
#pragma unroll
        for (int tm = 0; tm < 4; ++tm)
#pragma unroll
            for (int tn = 0; tn < 4; ++tn)
                acc[tm][tn] = __builtin_amdgcn_mfma_f32_16x16x32_f16(al[tm], bh[tn], acc[tm][tn], 0, 0, 0);
#pragma unroll
        for (int tm = 0; tm < 4; ++tm)
#pragma unroll
            for (int tn = 0; tn < 4; ++tn)
                acc[tm][tn] = __builtin_amdgcn_mfma_f32_16x16x32_f16(ah[tm], bh[tn], acc[tm][tn], 0, 0, 0);
    };

    const int nt = K >> 5;
    STAGE(0, 0);
    int cur = 0;
    for (int t = 0; t < nt - 1; ++t) {
        STAGE((t + 1) << 5, cur ^ 1);
        asm volatile("s_waitcnt vmcnt(8)" ::: "memory");
        __builtin_amdgcn_s_barrier();
        COMPUTE(cur);
        asm volatile("s_waitcnt lgkmcnt(0)" ::: "memory");
        __builtin_amdgcn_s_barrier();
        cur ^= 1;
    }
    asm volatile("s_waitcnt vmcnt(0)" ::: "memory");
    __builtin_amdgcn_s_barrier();
    COMPUTE(cur);

    if (MODE == 3) {
        // per-row partial argmin over this wave's 64 cols; slot = bx*2 + (w&1)
#pragma unroll
        for (int tm = 0; tm < 4; ++tm) {
#pragma unroll
            for (int r = 0; r < 4; ++r) {
                u64 key = ~0ull;
#pragma unroll
                for (int tn = 0; tn < 4; ++tn) {
                    const int c = bn + nBase + tn * 16 + (lane & 15);
                    float score = bias[c] - 2.0f * (acc[tm][tn][r] * INV_SASB);
                    u64 k = ((u64)f2ord(score) << 10) | (u32)c;
                    key = (k < key) ? k : key;
                }
#pragma unroll
                for (int m = 1; m < 16; m <<= 1) {
                    u64 o = __shfl_xor((unsigned long long)key, m);
                    key = (o < key) ? o : key;
                }
                if ((lane & 15) == 0) {
                    const int row = bm + mBase + tm * 16 + (lane >> 4) * 4 + r;
                    Part[(size_t)row * 16 + bx * 2 + (w & 1)] = key;
                }
            }
        }
        return;
    }

    // C/D frag layout col=lane&15, row=(lane>>4)*4+r
#pragma unroll
    for (int tm = 0; tm < 4; ++tm) {
        const int r0 = bm + mBase + tm * 16 + (lane >> 4) * 4;
#pragma unroll
        for (int tn = 0; tn < 4; ++tn) {
            const int c = bn + nBase + tn * 16 + (lane & 15);
            const float bvv = bias[c];
#pragma unroll
            for (int r = 0; r < 4; ++r) {
                float v = acc[tm][tn][r] * INV_SASB + bvv;
                if (MODE == 1) v = (v >= 0.f) ? v : 0.2f * v;
                const size_t o = (size_t)(r0 + r) * N + c;
                f16 hi, lo;
                splitf(v * SA, hi, lo);
                Oh[o] = hi;
                Ol[o] = lo;
            }
        }
    }
}

// ---------------- fp16x2 GEMM, 256^2 tile, 8 waves (MODE 1: encoder layer 1) ---------
template <int MODE>
__global__ __launch_bounds__(512) void gemm2w(
    const f16* __restrict__ Ahg, const f16* __restrict__ Alg,
    const f16* __restrict__ Bhg, const f16* __restrict__ Blg,
    const float* __restrict__ bias,
    f16* __restrict__ Oh, f16* __restrict__ Ol, u64* __restrict__ Part,
    int N, int K) {
    __shared__ f16 Ah[2 * 8192];
    __shared__ f16 Al[2 * 8192];
    __shared__ f16 Bh[2 * 8192];
    __shared__ f16 Bl[2 * 8192];
    const int w = threadIdx.x >> 6;
    const int lane = threadIdx.x & 63;
    int bx, by;
    xcd_swz(bx, by);
    const int bm = by * 256;
    const int bn = bx * 256;

    const int srow = w * 32 + (lane >> 2);
    const int scol = ((lane & 3) ^ ((lane >> 3) & 3)) * 8;
    const f16* AhG = Ahg + (size_t)(bm + srow) * K + scol;
    const f16* AlG = Alg + (size_t)(bm + srow) * K + scol;
    const f16* BhG = Bhg + (size_t)(bn + srow) * K + scol;
    const f16* BlG = Blg + (size_t)(bn + srow) * K + scol;
    f16* AhW = &Ah[(w * 32) * 32];
    f16* AlW = &Al[(w * 32) * 32];
    f16* BhW = &Bh[(w * 32) * 32];
    f16* BlW = &Bl[(w * 32) * 32];

    const int wc = w & 3;
    const int mBase = (w >> 2) * 128;
    const int nBase = wc * 64;
    const int co = ((lane >> 4) ^ (((lane & 15) >> 1) & 3)) * 8;

    f32x4 acc[8][4];
    const f32x4 z4 = {0.f, 0.f, 0.f, 0.f};
#pragma unroll
    for (int a = 0; a < 8; ++a)
#pragma unroll
        for (int b = 0; b < 4; ++b) acc[a][b] = z4;

    auto STAGE = [&](int k0, int b) {
        const int o = b << 13;
        gld16(AhG + k0, AhW + o);
        gld16(AhG + k0 + (size_t)16 * K, AhW + o + 512);
        gld16(AlG + k0, AlW + o);
        gld16(AlG + k0 + (size_t)16 * K, AlW + o + 512);
        gld16(BhG + k0, BhW + o);
        gld16(BhG + k0 + (size_t)16 * K, BhW + o + 512);
        gld16(BlG + k0, BlW + o);
        gld16(BlG + k0 + (size_t)16 * K, BlW + o + 512);
    };
    auto COMPUTE = [&](int b) {
        const int o = b << 13;
        v8hf bh4[4], bl4[4];
#pragma unroll
        for (int tn = 0; tn < 4; ++tn) {
            const int ro = o + (nBase + tn * 16 + (lane & 15)) * 32 + co;
            bh4[tn] = *(const v8hf*)&Bh[ro];
            bl4[tn] = *(const v8hf*)&Bl[ro];
        }
#pragma unroll
        for (int h = 0; h < 2; ++h) {
            v8hf ah4[4], al4[4];
#pragma unroll
            for (int j = 0; j < 4; ++j) {
                const int ro = o + (mBase + (h * 4 + j) * 16 + (lane & 15)) * 32 + co;
                ah4[j] = *(const v8hf*)&Ah[ro];
                al4[j] = *(const v8hf*)&Al[ro];
            }
            __builtin_amdgcn_s_setprio(1);
#pragma unroll
            for (int j = 0; j < 4; ++j)
#pragma unroll
                for (int tn = 0; tn < 4; ++tn)
                    acc[h * 4 + j][tn] = __builtin_amdgcn_mfma_f32_16x16x32_f16(ah4[j], bl4[tn], acc[h * 4 + j][tn], 0, 0, 0);
#pragma unroll
            for (int j = 0; j < 4; ++j)
#pragma unroll
                for (int tn = 0; tn < 4; ++tn)
                    acc[h * 4 + j][tn] = __builtin_amdgcn_mfma_f32_16x16x32_f16(al4[j], bh4[tn], acc[h * 4 + j][tn], 0, 0, 0);
#pragma unroll
            for (int j = 0; j < 4; ++j)
#pragma unroll
                for (int tn = 0; tn < 4; ++tn)
                    acc[h * 4 + j][tn] = __builtin_amdgcn_mfma_f32_16x16x32_f16(ah4[j], bh4[tn], acc[h * 4 + j][tn], 0, 0, 0);
            __builtin_amdgcn_s_setprio(0);
        }
    };

    const int nt = K >> 5;
    STAGE(0, 0);
    int cur = 0;
    for (int t = 0; t < nt - 1; ++t) {
        STAGE((t + 1) << 5, cur ^ 1);
        asm volatile("s_waitcnt vmcnt(8)" ::: "memory");
        __builtin_amdgcn_s_barrier();
        COMPUTE(cur);
        asm volatile("s_waitcnt lgkmcnt(0)" ::: "memory");
        __builtin_amdgcn_s_barrier();
        cur ^= 1;
    }
    asm volatile("s_waitcnt vmcnt(0)" ::: "memory");
    __builtin_amdgcn_s_barrier();
    COMPUTE(cur);

#pragma unroll
    for (int tm = 0; tm < 8; ++tm) {
        const int r0 = bm + mBase + tm * 16 + (lane >> 4) * 4;
#pragma unroll
        for (int tn = 0; tn < 4; ++tn) {
            const int c = bn + nBase + tn * 16 + (lane & 15);
            const float bvv = bias[c];
#pragma unroll
            for (int r = 0; r < 4; ++r) {
                float v = acc[tm][tn][r] * INV_SASB + bvv;
                if (MODE == 1) v = (v >= 0.f) ? v : 0.2f * v;
                const size_t o = (size_t)(r0 + r) * N + c;
                f16 hi, lo;
                splitf(v * SA, hi, lo);
                Oh[o] = hi;
                Ol[o] = lo;
            }
        }
    }
}

// ---------------- bf16 GEMM (decoder), 128^2; MODE 0 also folds the loss reduce ------
template <int MODE>
__global__ __launch_bounds__(256) void gemm_bt(
    const u16* __restrict__ A, const u16* __restrict__ B,
    const float* __restrict__ bias, void* __restrict__ Cout,
    int N, int K, int ldc, int Nreal,
    const float* __restrict__ lossPart, float* __restrict__ outLoss) {
    __shared__ u16 As[2 * 4096];
    __shared__ u16 Bs[2 * 4096];
    const int w = threadIdx.x >> 6;
    const int lane = threadIdx.x & 63;
    int bx, by;
    xcd_swz(bx, by);
    const int bm = by * 128;
    const int bn = bx * 128;

    const int srow = w * 32 + (lane >> 2);
    const int scol = ((lane & 3) ^ ((lane >> 3) & 3)) * 8;
    const u16* Ag = A + (size_t)(bm + srow) * K + scol;
    const u16* Bg = B + (size_t)(bn + srow) * K + scol;
    u16* AsW = &As[(w * 32) * 32];
    u16* BsW = &Bs[(w * 32) * 32];

    const int mBase = (w >> 1) * 64;
    const int nBase = (w & 1) * 64;
    const int co = ((lane >> 4) ^ (((lane & 15) >> 1) & 3)) * 8;

    f32x4 acc[4][4];
    const f32x4 z4 = {0.f, 0.f, 0.f, 0.f};
#pragma unroll
    for (int a = 0; a < 4; ++a)
#pragma unroll
        for (int b = 0; b < 4; ++b) acc[a][b] = z4;

    auto STAGE = [&](int k0, int b) {
        const int o = b << 12;
        gld16(Ag + k0, AsW + o);
        gld16(Ag + k0 + (size_t)16 * K, AsW + o + 16 * 32);
        gld16(Bg + k0, BsW + o);
        gld16(Bg + k0 + (size_t)16 * K, BsW + o + 16 * 32);
    };
    auto COMPUTE = [&](int b) {
        const int o = b << 12;
        v8bf af[4], bv[4];
#pragma unroll
        for (int t = 0; t < 4; ++t) {
            af[t] = *(const v8bf*)&As[o + (mBase + t * 16 + (lane & 15)) * 32 + co];
            bv[t] = *(const v8bf*)&Bs[o + (nBase + t * 16 + (lane & 15)) * 32 + co];
        }
#pragma unroll
        for (int tm = 0; tm < 4; ++tm)
#pragma unroll
            for (int tn = 0; tn < 4; ++tn)
                acc[tm][tn] = __builtin_amdgcn_mfma_f32_16x16x32_bf16(af[tm], bv[tn], acc[tm][tn], 0, 0, 0);
    };

    const int nt = K >> 5;
    STAGE(0, 0);
    int cur = 0;
    for (int t = 0; t < nt - 1; ++t) {
        STAGE((t + 1) << 5, cur ^ 1);
        asm volatile("s_waitcnt vmcnt(4)" ::: "memory");
        __builtin_amdgcn_s_barrier();
        COMPUTE(cur);
        asm volatile("s_waitcnt lgkmcnt(0)" ::: "memory");
        __builtin_amdgcn_s_barrier();
        cur ^= 1;
    }
    asm volatile("s_waitcnt vmcnt(0)" ::: "memory");
    __builtin_amdgcn_s_barrier();
    COMPUTE(cur);

#pragma unroll
    for (int tm = 0; tm < 4; ++tm) {
        const int r0 = bm + mBase + tm * 16 + (lane >> 4) * 4;
#pragma unroll
        for (int tn = 0; tn < 4; ++tn) {
            const int c = bn + nBase + tn * 16 + (lane & 15);
            if (MODE == 0 && c >= Nreal) continue;
            const float bvv = bias[c];
#pragma unroll
            for (int r = 0; r < 4; ++r) {
                float v = acc[tm][tn][r] + bvv;
                if (MODE == 1) v = (v >= 0.f) ? v : 0.2f * v;
                const size_t o = (size_t)(r0 + r) * ldc + c;
                if (MODE == 0)
                    ((float*)Cout)[o] = v;
                else
                    ((u16*)Cout)[o] = f2b(v);
            }
        }
    }

    // folded loss reduction (one physical block; lossPart written by vq2, a prior
    // dispatch in-stream -> globally visible)
    if (MODE == 0 && blockIdx.x == 0 && blockIdx.y == 0) {
        __shared__ float ls2[4];
        const int wv = threadIdx.x >> 6;
        float s = 0.f;
        for (int i = threadIdx.x; i < BATCH / 4; i += 256) s += lossPart[i];
        for (int off = 32; off > 0; off >>= 1) s += __shfl_down(s, off);
        if ((threadIdx.x & 63) == 0) ls2[wv] = s;
        __syncthreads();
        if (threadIdx.x == 0)
            outLoss[0] = 1.25f * (ls2[0] + ls2[1] + ls2[2] + ls2[3]) / (float)(BATCH * LATENT);
    }
}

// ---------------- VQ finish: reduce 16 partials/row, gather, loss partials; wave per row --------
__global__ __launch_bounds__(256) void vq2(
    const u64* __restrict__ Part, const float* __restrict__ embF,
    const f16* __restrict__ zh, const f16* __restrict__ zl,
    u16* __restrict__ qb, float* __restrict__ lossPart) {
    __shared__ float ls[4];
    const int lane = threadIdx.x & 63;
    const int wv = threadIdx.x >> 6;
    const int row = blockIdx.x * 4 + wv;

    u64 key = (lane < 16) ? Part[(size_t)row * 16 + lane] : ~0ull;
#pragma unroll
    for (int m = 1; m < 16; m <<= 1) {
        u64 o = __shfl_xor((unsigned long long)key, m);
        key = (o < key) ? o : key;
    }
    const int bidx = (int)(__shfl((unsigned long long)key, 0) & 1023ull);

    const float4 q0 = ((const float4*)(embF + (size_t)bidx * LATENT))[2 * lane];
    const float4 q1 = ((const float4*)(embF + (size_t)bidx * LATENT))[2 * lane + 1];
    float qf[8] = {q0.x, q0.y, q0.z, q0.w, q1.x, q1.y, q1.z, q1.w};
    u16 qpack[8];
#pragma unroll
    for (int t = 0; t < 8; ++t) qpack[t] = f2b(qf[t]);
    *(uint4*)(qb + (size_t)row * LATENT + lane * 8) = *(const uint4*)qpack;

    v8hf zh8 = *(const v8hf*)(zh + (size_t)row * LATENT + lane * 8);
    v8hf zl8 = *(const v8hf*)(zl + (size_t)row * LATENT + lane * 8);
    float s = 0.f;
#pragma unroll
    for (int t = 0; t < 8; ++t) {
        float z = ((float)zh8[t] + (float)zl8[t]) * (1.0f / SA);
        float df = qf[t] - z;
        s += df * df;
    }
    for (int off = 32; off > 0; off >>= 1) s += __shfl_down(s, off);
    if (lane == 0) ls[wv] = s;
    __syncthreads();
    if (threadIdx.x == 0) lossPart[blockIdx.x] = ls[0] + ls[1] + ls[2] + ls[3];
}

// ---------------- launch ----------------
extern "C" void kernel_launch(void* const* d_in, const int* in_sizes, int n_in,
                              void* d_out, int out_size, void* d_ws, size_t ws_size,
                              hipStream_t stream) {
    const float* x = (const float*)d_in[0];
    const float* W1 = (const float*)d_in[1];
    const float* b1 = (const float*)d_in[2];
    const float* W2 = (const float*)d_in[3];
    const float* b2 = (const float*)d_in[4];
    const float* emb = (const float*)d_in[5];
    const float* W3 = (const float*)d_in[6];
    const float* b3 = (const float*)d_in[7];
    const float* W4 = (const float*)d_in[8];
    const float* b4 = (const float*)d_in[9];
    float* out = (float*)d_out;

    char* ws = (char*)d_ws;
    size_t off = 0;
    auto alloc = [&](size_t bytes) {
        void* p = ws + off;
        off += (bytes + 255) & ~(size_t)255;
        return p;
    };
    char* A = (char*)alloc((size_t)BATCH * H_ENC * 2);
    char* Breg = (char*)alloc((size_t)BATCH * H_ENC * 2);
    char* C = (char*)alloc((size_t)BATCH * IN_PAD * 2 * 2);
    u16* qb = (u16*)alloc((size_t)BATCH * LATENT * 2);
    u64* Part = (u64*)alloc((size_t)BATCH * 16 * 8);
    float* lossPart = (float*)alloc((BATCH / 4) * 4);
    f16* W1Th = (f16*)alloc((size_t)H_ENC * IN_PAD * 2);
    f16* W1Tl = (f16*)alloc((size_t)H_ENC * IN_PAD * 2);
    f16* W2Th = (f16*)alloc((size_t)LATENT * H_ENC * 2);
    f16* W2Tl = (f16*)alloc((size_t)LATENT * H_ENC * 2);
    f16* eTh = (f16*)alloc((size_t)NUM_EMB * LATENT * 2);
    f16* eTl = (f16*)alloc((size_t)NUM_EMB * LATENT * 2);
    float* eTf = (float*)alloc((size_t)NUM_EMB * LATENT * 4);
    u16* W3T = (u16*)alloc((size_t)H_DEC * LATENT * 2);
    u16* W4T = (u16*)alloc((size_t)OUT_PAD * H_DEC * 2);
    float* enorm = (float*)alloc(NUM_EMB * 4);

    f16* h_hi = (f16*)A;
    f16* h_lo = (f16*)Breg;
    u16* h2 = (u16*)Breg;
    f16* xh = (f16*)C;
    f16* xl = xh + (size_t)BATCH * IN_PAD;
    f16* zh = (f16*)C;
    f16* zl = zh + (size_t)BATCH * LATENT;

    // single merged prep dispatch (was 7)
    prep<<<50564, 256, 0, stream>>>(x, W1, W2, emb, W3, W4, xh, xl,
                                    W1Th, W1Tl, W2Th, W2Tl, eTh, eTl, eTf, W3T, W4T, enorm);

    // encoder layer 1: 256^2 (K=704, 512 WGs) — the one shape where 256^2 wins
    gemm2w<1><<<dim3(H_ENC / 256, BATCH / 256), 512, 0, stream>>>(xh, xl, W1Th, W1Tl, b1, h_hi, h_lo, nullptr, H_ENC, IN_PAD);
    // encoder layer 2: 128^2
    gemm2<2><<<dim3(LATENT / 128, BATCH / 128), 256, 0, stream>>>(h_hi, h_lo, W2Th, W2Tl, b2, zh, zl, nullptr, LATENT, H_ENC);
    // distance pass: 128^2, argmin epilogue
    gemm2<3><<<dim3(NUM_EMB / 128, BATCH / 128), 256, 0, stream>>>(zh, zl, eTh, eTl, enorm, nullptr, nullptr, Part, NUM_EMB, LATENT);
    // VQ finish
    vq2<<<BATCH / 4, 256, 0, stream>>>(Part, eTf, zh, zl, qb, lossPart);
    // decoder (bf16, 128^2); last GEMM folds the loss reduction
    gemm_bt<1><<<dim3(H_DEC / 128, BATCH / 128), 256, 0, stream>>>(qb, W3T, b3, h2, H_DEC, LATENT, H_DEC, H_DEC, nullptr, nullptr);
    gemm_bt<0><<<dim3(OUT_PAD / 128, BATCH / 128), 256, 0, stream>>>(h2, W4T, b4, out, OUT_PAD, H_DEC, OUT_DIM, OUT_DIM, lossPart, out + (size_t)BATCH * OUT_DIM);

    (void)in_sizes; (void)n_in; (void)out_size; (void)ws_size;
}

// Round 6
// 589.914 us; speedup vs baseline: 1.0924x; 1.0018x over previous
//
#include <hip/hip_runtime.h>

typedef unsigned short u16;
typedef unsigned int u32;
typedef unsigned long long u64;
typedef __bf16 v8bf __attribute__((ext_vector_type(8)));
typedef _Float16 f16;
typedef _Float16 v8hf __attribute__((ext_vector_type(8)));
typedef float f32x4 __attribute__((ext_vector_type(4)));

#define BATCH 16384
#define IN_DIM 700
#define IN_PAD 704
#define H_ENC 2048
#define LATENT 512
#define H_DEC 2048
#define OUT_DIM 700
#define OUT_PAD 768
#define NUM_EMB 1024

// pre-scales keep split-hi (and nearly all split-lo) in fp16 normal range
#define SA 16.0f
#define SB 64.0f
#define INV_SASB 9.765625e-4f   // 2^-10 exact

__device__ __forceinline__ u16 f2b(float f) {  // round-to-nearest-even
    u32 x = __float_as_uint(f);
    u32 r = x + 0x7fffu + ((x >> 16) & 1u);
    return (u16)(r >> 16);
}
// unscaled residual split: v = hi + lo
__device__ __forceinline__ void splitf(float v, f16& hi, f16& lo) {
    hi = (f16)v;
    lo = (f16)(v - (float)hi);
}
// float -> monotone-orderable u32 (ascending)
__device__ __forceinline__ u32 f2ord(float f) {
    u32 u = __float_as_uint(f);
    return (u >> 31) ? ~u : (u | 0x80000000u);
}

// async global->LDS, 16B per lane; lds dest wave-uniform base (+lane*16 by HW)
__device__ __forceinline__ void gld16(const void* g, void* s) {
    __builtin_amdgcn_global_load_lds((const __attribute__((address_space(1))) void*)g,
                                     (__attribute__((address_space(3))) void*)s, 16, 0, 0);
}

// T1: bijective XCD-chunk swizzle (requires nwg % 8 == 0, true for all our grids).
// Verified R5: gemm2w<1> FETCH 186 MB -> 67.8 MB.
__device__ __forceinline__ void xcd_swz(int& bx, int& by) {
    const u32 nx = gridDim.x;
    const u32 p = blockIdx.y * nx + blockIdx.x;
    const u32 chunk = (nx * gridDim.y) >> 3;
    const u32 s = (p & 7u) * chunk + (p >> 3);
    bx = (int)(s % nx);
    by = (int)(s / nx);
}

// ---- LDS bank-conflict swizzle (row-pair XOR), verified R1: conflicts 1.15e7 -> 0 ----
//   write side: src col elems = ((lane&3) ^ ((lane>>3)&3)) * 8   (16-row periodic)
//   read  side: col elems     = ((lane>>4) ^ (((lane&15)>>1)&3)) * 8
// ---- R6: gemm2w phase-locked K-step (m201-style). Registers pinned: acc 128 AGPR +
// ~124 VGPR = 252/256 budget at 2 waves/SIMD -> all pipelining must be in-wave ILP.

// ---------------- merged prep kernel (was 7 dispatches) ----------------
__global__ __launch_bounds__(256) void prep(
    const float* __restrict__ x, const float* __restrict__ W1,
    const float* __restrict__ W2, const float* __restrict__ emb,
    const float* __restrict__ W3, const float* __restrict__ W4,
    f16* __restrict__ xh, f16* __restrict__ xl,
    f16* __restrict__ W1Th, f16* __restrict__ W1Tl,
    f16* __restrict__ W2Th, f16* __restrict__ W2Tl,
    f16* __restrict__ eTh, f16* __restrict__ eTl, float* __restrict__ eTf,
    u16* __restrict__ W3T, u16* __restrict__ W4T, float* __restrict__ enorm) {
    __shared__ float tile[32][33];
    const int b = blockIdx.x;
    const int t = threadIdx.x;

    if (b < 45056) {  // split_x: BATCH*IN_PAD = 45056*256 exactly
        const int idx = b * 256 + t;
        const int r = idx / IN_PAD, c = idx - r * IN_PAD;
        float v = (c < IN_DIM) ? x[(size_t)r * IN_DIM + c] * SA : 0.f;
        f16 hi, lo;
        splitf(v, hi, lo);
        xh[idx] = hi;
        xl[idx] = lo;
        return;
    }
    const int tx = t & 31, ty = t >> 5;

    auto ts = [&](const float* W, f16* Th, f16* Tl, float* Tf, int K, int N, int Kp,
                  float scale, int bx, int by) {
        const int kb = bx * 32, nb = by * 32;
        for (int i = ty; i < 32; i += 8) {
            int k = kb + i, n = nb + tx;
            tile[i][tx] = (k < K && n < N) ? W[(size_t)k * N + n] : 0.f;
        }
        __syncthreads();
        for (int i = ty; i < 32; i += 8) {
            int n = nb + i, kk = kb + tx;
            if (n < N && kk < Kp) {
                float v = tile[tx][i];
                if (Tf) Tf[(size_t)n * Kp + kk] = v;
                f16 hi, lo;
                splitf(v * scale, hi, lo);
                Th[(size_t)n * Kp + kk] = hi;
                Tl[(size_t)n * Kp + kk] = lo;
            }
        }
    };
    auto tp = [&](const float* W, u16* WT, int K, int N, int Kp, int Np, int bx, int by) {
        const int kb = bx * 32, nb = by * 32;
        for (int i = ty; i < 32; i += 8) {
            int k = kb + i, n = nb + tx;
            tile[i][tx] = (k < K && n < N) ? W[(size_t)k * N + n] : 0.f;
        }
        __syncthreads();
        for (int i = ty; i < 32; i += 8) {
            int n = nb + i, k = kb + tx;
            if (n < Np && k < Kp) WT[(size_t)n * Kp + k] = f2b(tile[tx][i]);
        }
    };

    if (b < 46464) {
        const int i = b - 45056;
        ts(W1, W1Th, W1Tl, nullptr, IN_DIM, H_ENC, IN_PAD, SB, i % 22, i / 22);
    } else if (b < 47488) {
        const int i = b - 46464;
        ts(W2, W2Th, W2Tl, nullptr, H_ENC, LATENT, H_ENC, SB, i % 64, i / 64);
    } else if (b < 48000) {
        const int i = b - 47488;
        ts(emb, eTh, eTl, eTf, LATENT, NUM_EMB, LATENT, SB, i % 16, i / 16);
    } else if (b < 49024) {
        const int i = b - 48000;
        tp(W3, W3T, LATENT, H_DEC, LATENT, H_DEC, i % 16, i / 16);
    } else if (b < 50560) {
        const int i = b - 49024;
        tp(W4, W4T, H_DEC, OUT_DIM, H_DEC, OUT_PAD, i % 64, i / 64);
    } else {
        const int n = (b - 50560) * 256 + t;
        if (n < NUM_EMB) {
            double s = 0.0;
            for (int k = 0; k < LATENT; ++k) {
                float v = emb[(size_t)k * NUM_EMB + n];
                s += (double)v * (double)v;
            }
            enorm[n] = (float)s;
        }
    }
}

// ---------------- fp16x2 GEMM, 128^2 tile (MODE 2: z store; MODE 3: VQ argmin) -------
template <int MODE>
__global__ __launch_bounds__(256) void gemm2(
    const f16* __restrict__ Ahg, const f16* __restrict__ Alg,
    const f16* __restrict__ Bhg, const f16* __restrict__ Blg,
    const float* __restrict__ bias,
    f16* __restrict__ Oh, f16* __restrict__ Ol, u64* __restrict__ Part,
    int N, int K) {
    __shared__ f16 Ah[2 * 4096];
    __shared__ f16 Al[2 * 4096];
    __shared__ f16 Bh[2 * 4096];
    __shared__ f16 Bl[2 * 4096];
    const int w = threadIdx.x >> 6;
    const int lane = threadIdx.x & 63;
    int bx, by;
    xcd_swz(bx, by);
    const int bm = by * 128;
    const int bn = bx * 128;

    const int srow = w * 32 + (lane >> 2);
    const int scol = ((lane & 3) ^ ((lane >> 3) & 3)) * 8;
    const f16* AhG = Ahg + (size_t)(bm + srow) * K + scol;
    const f16* AlG = Alg + (size_t)(bm + srow) * K + scol;
    const f16* BhG = Bhg + (size_t)(bn + srow) * K + scol;
    const f16* BlG = Blg + (size_t)(bn + srow) * K + scol;
    f16* AhW = &Ah[(w * 32) * 32];
    f16* AlW = &Al[(w * 32) * 32];
    f16* BhW = &Bh[(w * 32) * 32];
    f16* BlW = &Bl[(w * 32) * 32];

    const int mBase = (w >> 1) * 64;
    const int nBase = (w & 1) * 64;
    const int co = ((lane >> 4) ^ (((lane & 15) >> 1) & 3)) * 8;

    f32x4 acc[4][4];
    const f32x4 z4 = {0.f, 0.f, 0.f, 0.f};
#pragma unroll
    for (int a = 0; a < 4; ++a)
#pragma unroll
        for (int b = 0; b < 4; ++b) acc[a][b] = z4;

    auto STAGE = [&](int k0, int b) {
        const int o = b << 12;
        gld16(AhG + k0, AhW + o);
        gld16(AhG + k0 + (size_t)16 * K, AhW + o + 16 * 32);
        gld16(AlG + k0, AlW + o);
        gld16(AlG + k0 + (size_t)16 * K, AlW + o + 16 * 32);
        gld16(BhG + k0, BhW + o);
        gld16(BhG + k0 + (size_t)16 * K, BhW + o + 16 * 32);
        gld16(BlG + k0, BlW + o);
        gld16(BlG + k0 + (size_t)16 * K, BlW + o + 16 * 32);
    };
    auto COMPUTE = [&](int b) {
        const int o = b << 12;
        v8hf ah[4], al[4], bh[4], bl[4];
#pragma unroll
        for (int t = 0; t < 4; ++t) {
            const int ro = (t * 16 + (lane & 15)) * 32 + co;
            ah[t] = *(const v8hf*)&Ah[o + mBase * 32 + ro];
            al[t] = *(const v8hf*)&Al[o + mBase * 32 + ro];
            bh[t] = *(const v8hf*)&Bh[o + nBase * 32 + ro];
            bl[t] = *(const v8hf*)&Bl[o + nBase * 32 + ro];
        }
        // cross terms first (small), big hh term last — preserves their low bits
#pragma unroll
        for (int tm = 0; tm < 4; ++tm)
#pragma unroll
            for (int tn = 0; tn < 4; ++tn)
                acc[tm][tn] = __builtin_amdgcn_mfma_f32_16x16x32_f16(ah[tm], bl[tn], acc[tm][tn], 0, 0, 0);
#pragma unroll
        for (int tm = 0; tm < 4; ++tm)
#pragma unroll
            for (int tn = 0; tn < 4; ++tn)
                acc[tm][tn] = __builtin_amdgcn_mfma_f32_16x16x32_f16(al[tm], bh[tn], acc[tm][tn], 0, 0, 0);
#pragma unroll
        for (int tm = 0; tm < 4; ++tm)
#pragma unroll
            for (int tn = 0; tn < 4; ++tn)
                acc[tm][tn] = __builtin_amdgcn_mfma_f32_16x16x32_f16(ah[tm], bh[tn], acc[tm][tn], 0, 0, 0);
    };

    const int nt = K >> 5;
    STAGE(0, 0);
    int cur = 0;
    for (int t = 0; t < nt - 1; ++t) {
        STAGE((t + 1) << 5, cur ^ 1);
        asm volatile("s_waitcnt vmcnt(8)" ::: "memory");
        __builtin_amdgcn_s_barrier();
        COMPUTE(cur);
        asm volatile("s_waitcnt lgkmcnt(0)" ::: "memory");
        __builtin_amdgcn_s_barrier();
        cur ^= 1;
    }
    asm volatile("s_waitcnt vmcnt(0)" ::: "memory");
    __builtin_amdgcn_s_barrier();
    COMPUTE(cur);

    if (MODE == 3) {
        // per-row partial argmin over this wave's 64 cols; slot = bx*2 + (w&1)
#pragma unroll
        for (int tm = 0; tm < 4; ++tm) {
#pragma unroll
            for (int r = 0; r < 4; ++r) {
                u64 key = ~0ull;
#pragma unroll
                for (int tn = 0; tn < 4; ++tn) {
                    const int c = bn + nBase + tn * 16 + (lane & 15);
                    float score = bias[c] - 2.0f * (acc[tm][tn][r] * INV_SASB);
                    u64 k = ((u64)f2ord(score) << 10) | (u32)c;
                    key = (k < key) ? k : key;
                }
#pragma unroll
                for (int m = 1; m < 16; m <<= 1) {
                    u64 o = __shfl_xor((unsigned long long)key, m);
                    key = (o < key) ? o : key;
                }
                if ((lane & 15) == 0) {
                    const int row = bm + mBase + tm * 16 + (lane >> 4) * 4 + r;
                    Part[(size_t)row * 16 + bx * 2 + (w & 1)] = key;
                }
            }
        }
        return;
    }

    // C/D frag layout col=lane&15, row=(lane>>4)*4+r
#pragma unroll
    for (int tm = 0; tm < 4; ++tm) {
        const int r0 = bm + mBase + tm * 16 + (lane >> 4) * 4;
#pragma unroll
        for (int tn = 0; tn < 4; ++tn) {
            const int c = bn + nBase + tn * 16 + (lane & 15);
            const float bvv = bias[c];
#pragma unroll
            for (int r = 0; r < 4; ++r) {
                float v = acc[tm][tn][r] * INV_SASB + bvv;
                if (MODE == 1) v = (v >= 0.f) ? v : 0.2f * v;
                const size_t o = (size_t)(r0 + r) * N + c;
                f16 hi, lo;
                splitf(v * SA, hi, lo);
                Oh[o] = hi;
                Ol[o] = lo;
            }
        }
    }
}

// ---------------- fp16x2 GEMM, 256^2 tile, 8 waves, phase-locked K-step --------------
// R6: 5 phases per K-step — ph0 {RD_B + RD_A pair0}; ph1..3 {RD_A pair p, MFMA pair p-1};
// ph4 {MFMA pair3}. A-frag regs ping-pong between 2 sets (static indices). Barriers
// convoy waves; setprio densifies MFMA clusters. Register-neutral vs R5.
template <int MODE>
__global__ __launch_bounds__(512) void gemm2w(
    const f16* __restrict__ Ahg, const f16* __restrict__ Alg,
    const f16* __restrict__ Bhg, const f16* __restrict__ Blg,
    const float* __restrict__ bias,
    f16* __restrict__ Oh, f16* __restrict__ Ol, u64* __restrict__ Part,
    int N, int K) {
    __shared__ f16 Ah[2 * 8192];
    __shared__ f16 Al[2 * 8192];
    __shared__ f16 Bh[2 * 8192];
    __shared__ f16 Bl[2 * 8192];
    const int w = threadIdx.x >> 6;
    const int lane = threadIdx.x & 63;
    int bx, by;
    xcd_swz(bx, by);
    const int bm = by * 256;
    const int bn = bx * 256;

    const int srow = w * 32 + (lane >> 2);
    const int scol = ((lane & 3) ^ ((lane >> 3) & 3)) * 8;
    const f16* AhG = Ahg + (size_t)(bm + srow) * K + scol;
    const f16* AlG = Alg + (size_t)(bm + srow) * K + scol;
    const f16* BhG = Bhg + (size_t)(bn + srow) * K + scol;
    const f16* BlG = Blg + (size_t)(bn + srow) * K + scol;
    f16* AhW = &Ah[(w * 32) * 32];
    f16* AlW = &Al[(w * 32) * 32];
    f16* BhW = &Bh[(w * 32) * 32];
    f16* BlW = &Bl[(w * 32) * 32];

    const int mBase = (w >> 2) * 128;
    const int nBase = (w & 3) * 64;
    const int co = ((lane >> 4) ^ (((lane & 15) >> 1) & 3)) * 8;

    f32x4 acc[8][4];
    const f32x4 z4 = {0.f, 0.f, 0.f, 0.f};
#pragma unroll
    for (int a = 0; a < 8; ++a)
#pragma unroll
        for (int b = 0; b < 4; ++b) acc[a][b] = z4;

    // fragment registers: B (held full K-step), A in 2 ping-pong sets
    v8hf Bh4[4], Bl4[4];
    v8hf aH0[2], aL0[2], aH1[2], aL1[2];

    auto STAGE = [&](int k0, int b) {
        const int o = b << 13;
        gld16(AhG + k0, AhW + o);
        gld16(AhG + k0 + (size_t)16 * K, AhW + o + 512);
        gld16(AlG + k0, AlW + o);
        gld16(AlG + k0 + (size_t)16 * K, AlW + o + 512);
        gld16(BhG + k0, BhW + o);
        gld16(BhG + k0 + (size_t)16 * K, BhW + o + 512);
        gld16(BlG + k0, BlW + o);
        gld16(BlG + k0 + (size_t)16 * K, BlW + o + 512);
    };

// read B fragments for this tile (8 x ds_read_b128)
#define RD_B(o)                                                              \
    {                                                                        \
        _Pragma("unroll") for (int tn = 0; tn < 4; ++tn) {                   \
            const int ro = (o) + (nBase + tn * 16 + (lane & 15)) * 32 + co;  \
            Bh4[tn] = *(const v8hf*)&Bh[ro];                                 \
            Bl4[tn] = *(const v8hf*)&Bl[ro];                                 \
        }                                                                    \
    }
// read A pair (2 rows) into set s (4 x ds_read_b128)
#define RD_A(o, pair, s)                                                              \
    {                                                                                 \
        _Pragma("unroll") for (int j = 0; j < 2; ++j) {                               \
            const int ro = (o) + (mBase + ((pair)*2 + j) * 16 + (lane & 15)) * 32 + co; \
            aH##s[j] = *(const v8hf*)&Ah[ro];                                         \
            aL##s[j] = *(const v8hf*)&Al[ro];                                         \
        }                                                                             \
    }
// MFMA cluster for pair from set s (24 MFMA; per-acc order bl, bh-cross, hh)
#define MM(pair, s)                                                                                             \
    {                                                                                                           \
        __builtin_amdgcn_s_setprio(1);                                                                          \
        _Pragma("unroll") for (int j = 0; j < 2; ++j)                                                           \
            _Pragma("unroll") for (int tn = 0; tn < 4; ++tn)                                                    \
                acc[(pair)*2 + j][tn] = __builtin_amdgcn_mfma_f32_16x16x32_f16(aH##s[j], Bl4[tn], acc[(pair)*2 + j][tn], 0, 0, 0); \
        _Pragma("unroll") for (int j = 0; j < 2; ++j)                                                           \
            _Pragma("unroll") for (int tn = 0; tn < 4; ++tn)                                                    \
                acc[(pair)*2 + j][tn] = __builtin_amdgcn_mfma_f32_16x16x32_f16(aL##s[j], Bh4[tn], acc[(pair)*2 + j][tn], 0, 0, 0); \
        _Pragma("unroll") for (int j = 0; j < 2; ++j)                                                           \
            _Pragma("unroll") for (int tn = 0; tn < 4; ++tn)                                                    \
                acc[(pair)*2 + j][tn] = __builtin_amdgcn_mfma_f32_16x16x32_f16(aH##s[j], Bh4[tn], acc[(pair)*2 + j][tn], 0, 0, 0); \
        __builtin_amdgcn_s_setprio(0);                                                                          \
    }

    const int nt = K >> 5;
    // prologue: stage tiles 0 and 1, wait tile 0 (tile 1 stays in flight)
    STAGE(0, 0);
    if (nt > 1) STAGE(32, 1);
    asm volatile("s_waitcnt vmcnt(8)" ::: "memory");
    __builtin_amdgcn_s_barrier();

    for (int t = 0; t < nt; ++t) {
        if (t > 0) {
            if (t + 1 < nt) {
                STAGE((t + 1) << 5, (t + 1) & 1);
                asm volatile("s_waitcnt vmcnt(8)" ::: "memory");
            } else {
                asm volatile("s_waitcnt vmcnt(0)" ::: "memory");
            }
            __builtin_amdgcn_s_barrier();
        }
        const int o = (t & 1) << 13;
        // ph0: B + pair0 reads (MFMA idle; stage loads of t+1 in flight)
        RD_B(o);
        RD_A(o, 0, 0);
        __builtin_amdgcn_s_barrier();
        // ph1: read pair1 (set1), MFMA pair0 (set0)
        RD_A(o, 1, 1);
        MM(0, 0);
        __builtin_amdgcn_s_barrier();
        // ph2: read pair2 (set0), MFMA pair1 (set1)
        RD_A(o, 2, 0);
        MM(1, 1);
        __builtin_amdgcn_s_barrier();
        // ph3: read pair3 (set1), MFMA pair2 (set0); then drain reads so next STAGE
        // can't clobber buf[cur] under any wave (formal WAR guard, rule #18 fenced)
        RD_A(o, 3, 1);
        MM(2, 0);
        asm volatile("s_waitcnt lgkmcnt(0)" ::: "memory");
        __builtin_amdgcn_sched_barrier(0);
        __builtin_amdgcn_s_barrier();
        // ph4: MFMA pair3 (regs only; overlaps other waves' next-step head)
        MM(3, 1);
    }
#undef RD_B
#undef RD_A
#undef MM

    // C/D frag layout col=lane&15, row=(lane>>4)*4+r
#pragma unroll
    for (int tm = 0; tm < 8; ++tm) {
        const int r0 = bm + mBase + tm * 16 + (lane >> 4) * 4;
#pragma unroll
        for (int tn = 0; tn < 4; ++tn) {
            const int c = bn + nBase + tn * 16 + (lane & 15);
            const float bvv = bias[c];
#pragma unroll
            for (int r = 0; r < 4; ++r) {
                float v = acc[tm][tn][r] * INV_SASB + bvv;
                if (MODE == 1) v = (v >= 0.f) ? v : 0.2f * v;
                const size_t o = (size_t)(r0 + r) * N + c;
                f16 hi, lo;
                splitf(v * SA, hi, lo);
                Oh[o] = hi;
                Ol[o] = lo;
            }
        }
    }
}

// ---------------- bf16 GEMM (decoder), 128^2; MODE 0 also folds the loss reduce ------
template <int MODE>
__global__ __launch_bounds__(256) void gemm_bt(
    const u16* __restrict__ A, const u16* __restrict__ B,
    const float* __restrict__ bias, void* __restrict__ Cout,
    int N, int K, int ldc, int Nreal,
    const float* __restrict__ lossPart, float* __restrict__ outLoss) {
    __shared__ u16 As[2 * 4096];
    __shared__ u16 Bs[2 * 4096];
    const int w = threadIdx.x >> 6;
    const int lane = threadIdx.x & 63;
    int bx, by;
    xcd_swz(bx, by);
    const int bm = by * 128;
    const int bn = bx * 128;

    const int srow = w * 32 + (lane >> 2);
    const int scol = ((lane & 3) ^ ((lane >> 3) & 3)) * 8;
    const u16* Ag = A + (size_t)(bm + srow) * K + scol;
    const u16* Bg = B + (size_t)(bn + srow) * K + scol;
    u16* AsW = &As[(w * 32) * 32];
    u16* BsW = &Bs[(w * 32) * 32];

    const int mBase = (w >> 1) * 64;
    const int nBase = (w & 1) * 64;
    const int co = ((lane >> 4) ^ (((lane & 15) >> 1) & 3)) * 8;

    f32x4 acc[4][4];
    const f32x4 z4 = {0.f, 0.f, 0.f, 0.f};
#pragma unroll
    for (int a = 0; a < 4; ++a)
#pragma unroll
        for (int b = 0; b < 4; ++b) acc[a][b] = z4;

    auto STAGE = [&](int k0, int b) {
        const int o = b << 12;
        gld16(Ag + k0, AsW + o);
        gld16(Ag + k0 + (size_t)16 * K, AsW + o + 16 * 32);
        gld16(Bg + k0, BsW + o);
        gld16(Bg + k0 + (size_t)16 * K, BsW + o + 16 * 32);
    };
    auto COMPUTE = [&](int b) {
        const int o = b << 12;
        v8bf af[4], bv[4];
#pragma unroll
        for (int t = 0; t < 4; ++t) {
            af[t] = *(const v8bf*)&As[o + (mBase + t * 16 + (lane & 15)) * 32 + co];
            bv[t] = *(const v8bf*)&Bs[o + (nBase + t * 16 + (lane & 15)) * 32 + co];
        }
#pragma unroll
        for (int tm = 0; tm < 4; ++tm)
#pragma unroll
            for (int tn = 0; tn < 4; ++tn)
                acc[tm][tn] = __builtin_amdgcn_mfma_f32_16x16x32_bf16(af[tm], bv[tn], acc[tm][tn], 0, 0, 0);
    };

    const int nt = K >> 5;
    STAGE(0, 0);
    int cur = 0;
    for (int t = 0; t < nt - 1; ++t) {
        STAGE((t + 1) << 5, cur ^ 1);
        asm volatile("s_waitcnt vmcnt(4)" ::: "memory");
        __builtin_amdgcn_s_barrier();
        COMPUTE(cur);
        asm volatile("s_waitcnt lgkmcnt(0)" ::: "memory");
        __builtin_amdgcn_s_barrier();
        cur ^= 1;
    }
    asm volatile("s_waitcnt vmcnt(0)" ::: "memory");
    __builtin_amdgcn_s_barrier();
    COMPUTE(cur);

#pragma unroll
    for (int tm = 0; tm < 4; ++tm) {
        const int r0 = bm + mBase + tm * 16 + (lane >> 4) * 4;
#pragma unroll
        for (int tn = 0; tn < 4; ++tn) {
            const int c = bn + nBase + tn * 16 + (lane & 15);
            if (MODE == 0 && c >= Nreal) continue;
            const float bvv = bias[c];
#pragma unroll
            for (int r = 0; r < 4; ++r) {
                float v = acc[tm][tn][r] + bvv;
                if (MODE == 1) v = (v >= 0.f) ? v : 0.2f * v;
                const size_t o = (size_t)(r0 + r) * ldc + c;
                if (MODE == 0)
                    ((float*)Cout)[o] = v;
                else
                    ((u16*)Cout)[o] = f2b(v);
            }
        }
    }

    // folded loss reduction (one physical block; lossPart written by vq2, a prior
    // dispatch in-stream -> globally visible)
    if (MODE == 0 && blockIdx.x == 0 && blockIdx.y == 0) {
        __shared__ float ls2[4];
        const int wv = threadIdx.x >> 6;
        float s = 0.f;
        for (int i = threadIdx.x; i < BATCH / 4; i += 256) s += lossPart[i];
        for (int off = 32; off > 0; off >>= 1) s += __shfl_down(s, off);
        if ((threadIdx.x & 63) == 0) ls2[wv] = s;
        __syncthreads();
        if (threadIdx.x == 0)
            outLoss[0] = 1.25f * (ls2[0] + ls2[1] + ls2[2] + ls2[3]) / (float)(BATCH * LATENT);
    }
}

// ---------------- VQ finish: reduce 16 partials/row, gather, loss partials; wave per row --------
__global__ __launch_bounds__(256) void vq2(
    const u64* __restrict__ Part, const float* __restrict__ embF,
    const f16* __restrict__ zh, const f16* __restrict__ zl,
    u16* __restrict__ qb, float* __restrict__ lossPart) {
    __shared__ float ls[4];
    const int lane = threadIdx.x & 63;
    const int wv = threadIdx.x >> 6;
    const int row = blockIdx.x * 4 + wv;

    u64 key = (lane < 16) ? Part[(size_t)row * 16 + lane] : ~0ull;
#pragma unroll
    for (int m = 1; m < 16; m <<= 1) {
        u64 o = __shfl_xor((unsigned long long)key, m);
        key = (o < key) ? o : key;
    }
    const int bidx = (int)(__shfl((unsigned long long)key, 0) & 1023ull);

    const float4 q0 = ((const float4*)(embF + (size_t)bidx * LATENT))[2 * lane];
    const float4 q1 = ((const float4*)(embF + (size_t)bidx * LATENT))[2 * lane + 1];
    float qf[8] = {q0.x, q0.y, q0.z, q0.w, q1.x, q1.y, q1.z, q1.w};
    u16 qpack[8];
#pragma unroll
    for (int t = 0; t < 8; ++t) qpack[t] = f2b(qf[t]);
    *(uint4*)(qb + (size_t)row * LATENT + lane * 8) = *(const uint4*)qpack;

    v8hf zh8 = *(const v8hf*)(zh + (size_t)row * LATENT + lane * 8);
    v8hf zl8 = *(const v8hf*)(zl + (size_t)row * LATENT + lane * 8);
    float s = 0.f;
#pragma unroll
    for (int t = 0; t < 8; ++t) {
        float z = ((float)zh8[t] + (float)zl8[t]) * (1.0f / SA);
        float df = qf[t] - z;
        s += df * df;
    }
    for (int off = 32; off > 0; off >>= 1) s += __shfl_down(s, off);
    if (lane == 0) ls[wv] = s;
    __syncthreads();
    if (threadIdx.x == 0) lossPart[blockIdx.x] = ls[0] + ls[1] + ls[2] + ls[3];
}

// ---------------- launch ----------------
extern "C" void kernel_launch(void* const* d_in, const int* in_sizes, int n_in,
                              void* d_out, int out_size, void* d_ws, size_t ws_size,
                              hipStream_t stream) {
    const float* x = (const float*)d_in[0];
    const float* W1 = (const float*)d_in[1];
    const float* b1 = (const float*)d_in[2];
    const float* W2 = (const float*)d_in[3];
    const float* b2 = (const float*)d_in[4];
    const float* emb = (const float*)d_in[5];
    const float* W3 = (const float*)d_in[6];
    const float* b3 = (const float*)d_in[7];
    const float* W4 = (const float*)d_in[8];
    const float* b4 = (const float*)d_in[9];
    float* out = (float*)d_out;

    char* ws = (char*)d_ws;
    size_t off = 0;
    auto alloc = [&](size_t bytes) {
        void* p = ws + off;
        off += (bytes + 255) & ~(size_t)255;
        return p;
    };
    char* A = (char*)alloc((size_t)BATCH * H_ENC * 2);
    char* Breg = (char*)alloc((size_t)BATCH * H_ENC * 2);
    char* C = (char*)alloc((size_t)BATCH * IN_PAD * 2 * 2);
    u16* qb = (u16*)alloc((size_t)BATCH * LATENT * 2);
    u64* Part = (u64*)alloc((size_t)BATCH * 16 * 8);
    float* lossPart = (float*)alloc((BATCH / 4) * 4);
    f16* W1Th = (f16*)alloc((size_t)H_ENC * IN_PAD * 2);
    f16* W1Tl = (f16*)alloc((size_t)H_ENC * IN_PAD * 2);
    f16* W2Th = (f16*)alloc((size_t)LATENT * H_ENC * 2);
    f16* W2Tl = (f16*)alloc((size_t)LATENT * H_ENC * 2);
    f16* eTh = (f16*)alloc((size_t)NUM_EMB * LATENT * 2);
    f16* eTl = (f16*)alloc((size_t)NUM_EMB * LATENT * 2);
    float* eTf = (float*)alloc((size_t)NUM_EMB * LATENT * 4);
    u16* W3T = (u16*)alloc((size_t)H_DEC * LATENT * 2);
    u16* W4T = (u16*)alloc((size_t)OUT_PAD * H_DEC * 2);
    float* enorm = (float*)alloc(NUM_EMB * 4);

    f16* h_hi = (f16*)A;
    f16* h_lo = (f16*)Breg;
    u16* h2 = (u16*)Breg;
    f16* xh = (f16*)C;
    f16* xl = xh + (size_t)BATCH * IN_PAD;
    f16* zh = (f16*)C;
    f16* zl = zh + (size_t)BATCH * LATENT;

    // single merged prep dispatch
    prep<<<50564, 256, 0, stream>>>(x, W1, W2, emb, W3, W4, xh, xl,
                                    W1Th, W1Tl, W2Th, W2Tl, eTh, eTl, eTf, W3T, W4T, enorm);

    // encoder layer 1: 256^2 phase-locked (K=704, 512 WGs)
    gemm2w<1><<<dim3(H_ENC / 256, BATCH / 256), 512, 0, stream>>>(xh, xl, W1Th, W1Tl, b1, h_hi, h_lo, nullptr, H_ENC, IN_PAD);
    // encoder layer 2: 128^2
    gemm2<2><<<dim3(LATENT / 128, BATCH / 128), 256, 0, stream>>>(h_hi, h_lo, W2Th, W2Tl, b2, zh, zl, nullptr, LATENT, H_ENC);
    // distance pass: 128^2, argmin epilogue
    gemm2<3><<<dim3(NUM_EMB / 128, BATCH / 128), 256, 0, stream>>>(zh, zl, eTh, eTl, enorm, nullptr, nullptr, Part, NUM_EMB, LATENT);
    // VQ finish
    vq2<<<BATCH / 4, 256, 0, stream>>>(Part, eTf, zh, zl, qb, lossPart);
    // decoder (bf16, 128^2); last GEMM folds the loss reduction
    gemm_bt<1><<<dim3(H_DEC / 128, BATCH / 128), 256, 0, stream>>>(qb, W3T, b3, h2, H_DEC, LATENT, H_DEC, H_DEC, nullptr, nullptr);
    gemm_bt<0><<<dim3(OUT_PAD / 128, BATCH / 128), 256, 0, stream>>>(h2, W4T, b4, out, OUT_PAD, H_DEC, OUT_DIM, OUT_DIM, lossPart, out + (size_t)BATCH * OUT_DIM);

    (void)in_sizes; (void)n_in; (void)out_size; (void)ws_size;
}

// Round 7
// 584.201 us; speedup vs baseline: 1.1030x; 1.0098x over previous
//
#include <hip/hip_runtime.h>

typedef unsigned short u16;
typedef unsigned int u32;
typedef unsigned long long u64;
typedef __bf16 v8bf __attribute__((ext_vector_type(8)));
typedef _Float16 f16;
typedef _Float16 v8hf __attribute__((ext_vector_type(8)));
typedef float f32x4 __attribute__((ext_vector_type(4)));
typedef float f32x16 __attribute__((ext_vector_type(16)));

#define BATCH 16384
#define IN_DIM 700
#define IN_PAD 704
#define H_ENC 2048
#define LATENT 512
#define H_DEC 2048
#define OUT_DIM 700
#define OUT_PAD 768
#define NUM_EMB 1024

// pre-scales keep split-hi (and nearly all split-lo) in fp16 normal range
#define SA 16.0f
#define SB 64.0f
#define INV_SASB 9.765625e-4f   // 2^-10 exact

__device__ __forceinline__ u16 f2b(float f) {  // round-to-nearest-even
    u32 x = __float_as_uint(f);
    u32 r = x + 0x7fffu + ((x >> 16) & 1u);
    return (u16)(r >> 16);
}
// unscaled residual split: v = hi + lo
__device__ __forceinline__ void splitf(float v, f16& hi, f16& lo) {
    hi = (f16)v;
    lo = (f16)(v - (float)hi);
}
// float -> monotone-orderable u32 (ascending)
__device__ __forceinline__ u32 f2ord(float f) {
    u32 u = __float_as_uint(f);
    return (u >> 31) ? ~u : (u | 0x80000000u);
}

// async global->LDS, 16B per lane; lds dest wave-uniform base (+lane*16 by HW)
__device__ __forceinline__ void gld16(const void* g, void* s) {
    __builtin_amdgcn_global_load_lds((const __attribute__((address_space(1))) void*)g,
                                     (__attribute__((address_space(3))) void*)s, 16, 0, 0);
}

// T1: bijective XCD-chunk swizzle (requires nwg % 8 == 0, true for all our grids).
// Verified R5: gemm2w<1> FETCH 186 MB -> 67.8 MB.
__device__ __forceinline__ void xcd_swz(int& bx, int& by) {
    const u32 nx = gridDim.x;
    const u32 p = blockIdx.y * nx + blockIdx.x;
    const u32 chunk = (nx * gridDim.y) >> 3;
    const u32 s = (p & 7u) * chunk + (p >> 3);
    bx = (int)(s % nx);
    by = (int)(s / nx);
}

// ---- LDS bank-conflict swizzle (row-pair XOR), verified R1: conflicts 1.15e7 -> 0 ----
//   write side: src col elems = ((lane&3) ^ ((lane>>3)&3)) * 8   (16-row periodic)
//   16x16 read: col elems     = ((lane>>4) ^ (((lane&15)>>1)&3)) * 8   (lane-constant)
//   32x32 read: physical slot = (kh*2 + (lane>>5)) ^ ((row>>1)&3)      (per-lane row)
//   Derived: 32-lane row groups at fixed logical slot land on slots 0,4,1,5,2,6,3,7
//   over 8 consecutive rows -> 8 lanes/slot = b128 floor, conflict-free.
// ---- K-loop: R5-verified 2-barrier dbuf + counted vmcnt. R6's 5-phase split
//   regressed (-8%, m196's coarse-phase warning reproduced) and is reverted.

// ---------------- merged prep kernel (was 7 dispatches) ----------------
__global__ __launch_bounds__(256) void prep(
    const float* __restrict__ x, const float* __restrict__ W1,
    const float* __restrict__ W2, const float* __restrict__ emb,
    const float* __restrict__ W3, const float* __restrict__ W4,
    f16* __restrict__ xh, f16* __restrict__ xl,
    f16* __restrict__ W1Th, f16* __restrict__ W1Tl,
    f16* __restrict__ W2Th, f16* __restrict__ W2Tl,
    f16* __restrict__ eTh, f16* __restrict__ eTl, float* __restrict__ eTf,
    u16* __restrict__ W3T, u16* __restrict__ W4T, float* __restrict__ enorm) {
    __shared__ float tile[32][33];
    const int b = blockIdx.x;
    const int t = threadIdx.x;

    if (b < 45056) {  // split_x: BATCH*IN_PAD = 45056*256 exactly
        const int idx = b * 256 + t;
        const int r = idx / IN_PAD, c = idx - r * IN_PAD;
        float v = (c < IN_DIM) ? x[(size_t)r * IN_DIM + c] * SA : 0.f;
        f16 hi, lo;
        splitf(v, hi, lo);
        xh[idx] = hi;
        xl[idx] = lo;
        return;
    }
    const int tx = t & 31, ty = t >> 5;

    auto ts = [&](const float* W, f16* Th, f16* Tl, float* Tf, int K, int N, int Kp,
                  float scale, int bx, int by) {
        const int kb = bx * 32, nb = by * 32;
        for (int i = ty; i < 32; i += 8) {
            int k = kb + i, n = nb + tx;
            tile[i][tx] = (k < K && n < N) ? W[(size_t)k * N + n] : 0.f;
        }
        __syncthreads();
        for (int i = ty; i < 32; i += 8) {
            int n = nb + i, kk = kb + tx;
            if (n < N && kk < Kp) {
                float v = tile[tx][i];
                if (Tf) Tf[(size_t)n * Kp + kk] = v;
                f16 hi, lo;
                splitf(v * scale, hi, lo);
                Th[(size_t)n * Kp + kk] = hi;
                Tl[(size_t)n * Kp + kk] = lo;
            }
        }
    };
    auto tp = [&](const float* W, u16* WT, int K, int N, int Kp, int Np, int bx, int by) {
        const int kb = bx * 32, nb = by * 32;
        for (int i = ty; i < 32; i += 8) {
            int k = kb + i, n = nb + tx;
            tile[i][tx] = (k < K && n < N) ? W[(size_t)k * N + n] : 0.f;
        }
        __syncthreads();
        for (int i = ty; i < 32; i += 8) {
            int n = nb + i, k = kb + tx;
            if (n < Np && k < Kp) WT[(size_t)n * Kp + k] = f2b(tile[tx][i]);
        }
    };

    if (b < 46464) {
        const int i = b - 45056;
        ts(W1, W1Th, W1Tl, nullptr, IN_DIM, H_ENC, IN_PAD, SB, i % 22, i / 22);
    } else if (b < 47488) {
        const int i = b - 46464;
        ts(W2, W2Th, W2Tl, nullptr, H_ENC, LATENT, H_ENC, SB, i % 64, i / 64);
    } else if (b < 48000) {
        const int i = b - 47488;
        ts(emb, eTh, eTl, eTf, LATENT, NUM_EMB, LATENT, SB, i % 16, i / 16);
    } else if (b < 49024) {
        const int i = b - 48000;
        tp(W3, W3T, LATENT, H_DEC, LATENT, H_DEC, i % 16, i / 16);
    } else if (b < 50560) {
        const int i = b - 49024;
        tp(W4, W4T, H_DEC, OUT_DIM, H_DEC, OUT_PAD, i % 64, i / 64);
    } else {
        const int n = (b - 50560) * 256 + t;
        if (n < NUM_EMB) {
            double s = 0.0;
            for (int k = 0; k < LATENT; ++k) {
                float v = emb[(size_t)k * NUM_EMB + n];
                s += (double)v * (double)v;
            }
            enorm[n] = (float)s;
        }
    }
}

// ---------------- fp16x2 GEMM, 128^2 tile (MODE 2: z store; MODE 3: VQ argmin) -------
template <int MODE>
__global__ __launch_bounds__(256) void gemm2(
    const f16* __restrict__ Ahg, const f16* __restrict__ Alg,
    const f16* __restrict__ Bhg, const f16* __restrict__ Blg,
    const float* __restrict__ bias,
    f16* __restrict__ Oh, f16* __restrict__ Ol, u64* __restrict__ Part,
    int N, int K) {
    __shared__ f16 Ah[2 * 4096];
    __shared__ f16 Al[2 * 4096];
    __shared__ f16 Bh[2 * 4096];
    __shared__ f16 Bl[2 * 4096];
    const int w = threadIdx.x >> 6;
    const int lane = threadIdx.x & 63;
    int bx, by;
    xcd_swz(bx, by);
    const int bm = by * 128;
    const int bn = bx * 128;

    const int srow = w * 32 + (lane >> 2);
    const int scol = ((lane & 3) ^ ((lane >> 3) & 3)) * 8;
    const f16* AhG = Ahg + (size_t)(bm + srow) * K + scol;
    const f16* AlG = Alg + (size_t)(bm + srow) * K + scol;
    const f16* BhG = Bhg + (size_t)(bn + srow) * K + scol;
    const f16* BlG = Blg + (size_t)(bn + srow) * K + scol;
    f16* AhW = &Ah[(w * 32) * 32];
    f16* AlW = &Al[(w * 32) * 32];
    f16* BhW = &Bh[(w * 32) * 32];
    f16* BlW = &Bl[(w * 32) * 32];

    const int mBase = (w >> 1) * 64;
    const int nBase = (w & 1) * 64;
    const int co = ((lane >> 4) ^ (((lane & 15) >> 1) & 3)) * 8;

    f32x4 acc[4][4];
    const f32x4 z4 = {0.f, 0.f, 0.f, 0.f};
#pragma unroll
    for (int a = 0; a < 4; ++a)
#pragma unroll
        for (int b = 0; b < 4; ++b) acc[a][b] = z4;

    auto STAGE = [&](int k0, int b) {
        const int o = b << 12;
        gld16(AhG + k0, AhW + o);
        gld16(AhG + k0 + (size_t)16 * K, AhW + o + 16 * 32);
        gld16(AlG + k0, AlW + o);
        gld16(AlG + k0 + (size_t)16 * K, AlW + o + 16 * 32);
        gld16(BhG + k0, BhW + o);
        gld16(BhG + k0 + (size_t)16 * K, BhW + o + 16 * 32);
        gld16(BlG + k0, BlW + o);
        gld16(BlG + k0 + (size_t)16 * K, BlW + o + 16 * 32);
    };
    auto COMPUTE = [&](int b) {
        const int o = b << 12;
        v8hf ah[4], al[4], bh[4], bl[4];
#pragma unroll
        for (int t = 0; t < 4; ++t) {
            const int ro = (t * 16 + (lane & 15)) * 32 + co;
            ah[t] = *(const v8hf*)&Ah[o + mBase * 32 + ro];
            al[t] = *(const v8hf*)&Al[o + mBase * 32 + ro];
            bh[t] = *(const v8hf*)&Bh[o + nBase * 32 + ro];
            bl[t] = *(const v8hf*)&Bl[o + nBase * 32 + ro];
        }
        // cross terms first (small), big hh term last — preserves their low bits
#pragma unroll
        for (int tm = 0; tm < 4; ++tm)
#pragma unroll
            for (int tn = 0; tn < 4; ++tn)
                acc[tm][tn] = __builtin_amdgcn_mfma_f32_16x16x32_f16(ah[tm], bl[tn], acc[tm][tn], 0, 0, 0);
#pragma unroll
        for (int tm = 0; tm < 4; ++tm)
#pragma unroll
            for (int tn = 0; tn < 4; ++tn)
                acc[tm][tn] = __builtin_amdgcn_mfma_f32_16x16x32_f16(al[tm], bh[tn], acc[tm][tn], 0, 0, 0);
#pragma unroll
        for (int tm = 0; tm < 4; ++tm)
#pragma unroll
            for (int tn = 0; tn < 4; ++tn)
                acc[tm][tn] = __builtin_amdgcn_mfma_f32_16x16x32_f16(ah[tm], bh[tn], acc[tm][tn], 0, 0, 0);
    };

    const int nt = K >> 5;
    STAGE(0, 0);
    int cur = 0;
    for (int t = 0; t < nt - 1; ++t) {
        STAGE((t + 1) << 5, cur ^ 1);
        asm volatile("s_waitcnt vmcnt(8)" ::: "memory");
        __builtin_amdgcn_s_barrier();
        COMPUTE(cur);
        asm volatile("s_waitcnt lgkmcnt(0)" ::: "memory");
        __builtin_amdgcn_s_barrier();
        cur ^= 1;
    }
    asm volatile("s_waitcnt vmcnt(0)" ::: "memory");
    __builtin_amdgcn_s_barrier();
    COMPUTE(cur);

    if (MODE == 3) {
        // per-row partial argmin over this wave's 64 cols; slot = bx*2 + (w&1)
#pragma unroll
        for (int tm = 0; tm < 4; ++tm) {
#pragma unroll
            for (int r = 0; r < 4; ++r) {
                u64 key = ~0ull;
#pragma unroll
                for (int tn = 0; tn < 4; ++tn) {
                    const int c = bn + nBase + tn * 16 + (lane & 15);
                    float score = bias[c] - 2.0f * (acc[tm][tn][r] * INV_SASB);
                    u64 k = ((u64)f2ord(score) << 10) | (u32)c;
                    key = (k < key) ? k : key;
                }
#pragma unroll
                for (int m = 1; m < 16; m <<= 1) {
                    u64 o = __shfl_xor((unsigned long long)key, m);
                    key = (o < key) ? o : key;
                }
                if ((lane & 15) == 0) {
                    const int row = bm + mBase + tm * 16 + (lane >> 4) * 4 + r;
                    Part[(size_t)row * 16 + bx * 2 + (w & 1)] = key;
                }
            }
        }
        return;
    }

    // C/D frag layout col=lane&15, row=(lane>>4)*4+r
#pragma unroll
    for (int tm = 0; tm < 4; ++tm) {
        const int r0 = bm + mBase + tm * 16 + (lane >> 4) * 4;
#pragma unroll
        for (int tn = 0; tn < 4; ++tn) {
            const int c = bn + nBase + tn * 16 + (lane & 15);
            const float bvv = bias[c];
#pragma unroll
            for (int r = 0; r < 4; ++r) {
                float v = acc[tm][tn][r] * INV_SASB + bvv;
                if (MODE == 1) v = (v >= 0.f) ? v : 0.2f * v;
                const size_t o = (size_t)(r0 + r) * N + c;
                f16 hi, lo;
                splitf(v * SA, hi, lo);
                Oh[o] = hi;
                Ol[o] = lo;
            }
        }
    }
}

// ---------------- fp16x2 GEMM, 256^2 tile, 8 waves, 32x32x16 MFMA (MODE 1) -----------
// R7: same R5-verified 2-barrier loop; math switched to mfma_f32_32x32x16_f16 —
// half the MFMA instructions for the same FLOP, +15% pipe ceiling (m06/m119).
// Wave: 4 M-blocks x 2 N-blocks of 32x32; acc 8 x f32x16 (128 AGPR, unchanged).
template <int MODE>
__global__ __launch_bounds__(512) void gemm2w(
    const f16* __restrict__ Ahg, const f16* __restrict__ Alg,
    const f16* __restrict__ Bhg, const f16* __restrict__ Blg,
    const float* __restrict__ bias,
    f16* __restrict__ Oh, f16* __restrict__ Ol, u64* __restrict__ Part,
    int N, int K) {
    __shared__ f16 Ah[2 * 8192];
    __shared__ f16 Al[2 * 8192];
    __shared__ f16 Bh[2 * 8192];
    __shared__ f16 Bl[2 * 8192];
    const int w = threadIdx.x >> 6;
    const int lane = threadIdx.x & 63;
    int bx, by;
    xcd_swz(bx, by);
    const int bm = by * 256;
    const int bn = bx * 256;

    const int srow = w * 32 + (lane >> 2);
    const int scol = ((lane & 3) ^ ((lane >> 3) & 3)) * 8;
    const f16* AhG = Ahg + (size_t)(bm + srow) * K + scol;
    const f16* AlG = Alg + (size_t)(bm + srow) * K + scol;
    const f16* BhG = Bhg + (size_t)(bn + srow) * K + scol;
    const f16* BlG = Blg + (size_t)(bn + srow) * K + scol;
    f16* AhW = &Ah[(w * 32) * 32];
    f16* AlW = &Al[(w * 32) * 32];
    f16* BhW = &Bh[(w * 32) * 32];
    f16* BlW = &Bl[(w * 32) * 32];

    const int mBase = (w >> 2) * 128;
    const int nBase = (w & 3) * 64;
    const int l31 = lane & 31, l5 = lane >> 5;

    f32x16 acc[4][2];
#pragma unroll
    for (int a = 0; a < 4; ++a)
#pragma unroll
        for (int b = 0; b < 2; ++b)
#pragma unroll
            for (int r = 0; r < 16; ++r) acc[a][b][r] = 0.f;

    auto STAGE = [&](int k0, int b) {
        const int o = b << 13;
        gld16(AhG + k0, AhW + o);
        gld16(AhG + k0 + (size_t)16 * K, AhW + o + 512);
        gld16(AlG + k0, AlW + o);
        gld16(AlG + k0 + (size_t)16 * K, AlW + o + 512);
        gld16(BhG + k0, BhW + o);
        gld16(BhG + k0 + (size_t)16 * K, BhW + o + 512);
        gld16(BlG + k0, BlW + o);
        gld16(BlG + k0 + (size_t)16 * K, BlW + o + 512);
    };
    auto COMPUTE = [&](int b) {
        const int o = b << 13;
        // B fragments: [nblk][khalf], 32x32x16 layout (col=l&31, k=(l>>5)*8+j)
        v8hf bH[2][2], bL[2][2];
#pragma unroll
        for (int n = 0; n < 2; ++n)
#pragma unroll
            for (int kh = 0; kh < 2; ++kh) {
                const int rr = nBase + n * 32 + l31;
                const int ro = o + rr * 32 + (((kh * 2 + l5) ^ ((rr >> 1) & 3)) * 8);
                bH[n][kh] = *(const v8hf*)&Bh[ro];
                bL[n][kh] = *(const v8hf*)&Bl[ro];
            }
#pragma unroll
        for (int hf = 0; hf < 2; ++hf) {
            v8hf aH[2][2], aL[2][2];
#pragma unroll
            for (int m = 0; m < 2; ++m)
#pragma unroll
                for (int kh = 0; kh < 2; ++kh) {
                    const int rr = mBase + (hf * 2 + m) * 32 + l31;
                    const int ro = o + rr * 32 + (((kh * 2 + l5) ^ ((rr >> 1) & 3)) * 8);
                    aH[m][kh] = *(const v8hf*)&Ah[ro];
                    aL[m][kh] = *(const v8hf*)&Al[ro];
                }
            __builtin_amdgcn_s_setprio(1);
            // cross terms first (small), big hh term last — preserves their low bits
#pragma unroll
            for (int m = 0; m < 2; ++m)
#pragma unroll
                for (int n = 0; n < 2; ++n)
#pragma unroll
                    for (int kh = 0; kh < 2; ++kh)
                        acc[hf * 2 + m][n] = __builtin_amdgcn_mfma_f32_32x32x16_f16(aH[m][kh], bL[n][kh], acc[hf * 2 + m][n], 0, 0, 0);
#pragma unroll
            for (int m = 0; m < 2; ++m)
#pragma unroll
                for (int n = 0; n < 2; ++n)
#pragma unroll
                    for (int kh = 0; kh < 2; ++kh)
                        acc[hf * 2 + m][n] = __builtin_amdgcn_mfma_f32_32x32x16_f16(aL[m][kh], bH[n][kh], acc[hf * 2 + m][n], 0, 0, 0);
#pragma unroll
            for (int m = 0; m < 2; ++m)
#pragma unroll
                for (int n = 0; n < 2; ++n)
#pragma unroll
                    for (int kh = 0; kh < 2; ++kh)
                        acc[hf * 2 + m][n] = __builtin_amdgcn_mfma_f32_32x32x16_f16(aH[m][kh], bH[n][kh], acc[hf * 2 + m][n], 0, 0, 0);
            __builtin_amdgcn_s_setprio(0);
        }
    };

    const int nt = K >> 5;
    STAGE(0, 0);
    int cur = 0;
    for (int t = 0; t < nt - 1; ++t) {
        STAGE((t + 1) << 5, cur ^ 1);
        asm volatile("s_waitcnt vmcnt(8)" ::: "memory");
        __builtin_amdgcn_s_barrier();
        COMPUTE(cur);
        asm volatile("s_waitcnt lgkmcnt(0)" ::: "memory");
        __builtin_amdgcn_s_barrier();
        cur ^= 1;
    }
    asm volatile("s_waitcnt vmcnt(0)" ::: "memory");
    __builtin_amdgcn_s_barrier();
    COMPUTE(cur);

    // C/D layout (32x32, m74/m101): col = lane&31, row = (reg&3)+8*(reg>>2)+4*(lane>>5)
#pragma unroll
    for (int mb = 0; mb < 4; ++mb) {
        const int r0 = bm + mBase + mb * 32 + 4 * l5;
#pragma unroll
        for (int nb = 0; nb < 2; ++nb) {
            const int c = bn + nBase + nb * 32 + l31;
            const float bvv = bias[c];
#pragma unroll
            for (int reg = 0; reg < 16; ++reg) {
                const int row = r0 + (reg & 3) + 8 * (reg >> 2);
                float v = acc[mb][nb][reg] * INV_SASB + bvv;
                if (MODE == 1) v = (v >= 0.f) ? v : 0.2f * v;
                const size_t o = (size_t)row * N + c;
                f16 hi, lo;
                splitf(v * SA, hi, lo);
                Oh[o] = hi;
                Ol[o] = lo;
            }
        }
    }
}

// ---------------- bf16 GEMM (decoder), 128^2; MODE 0 also folds the loss reduce ------
template <int MODE>
__global__ __launch_bounds__(256) void gemm_bt(
    const u16* __restrict__ A, const u16* __restrict__ B,
    const float* __restrict__ bias, void* __restrict__ Cout,
    int N, int K, int ldc, int Nreal,
    const float* __restrict__ lossPart, float* __restrict__ outLoss) {
    __shared__ u16 As[2 * 4096];
    __shared__ u16 Bs[2 * 4096];
    const int w = threadIdx.x >> 6;
    const int lane = threadIdx.x & 63;
    int bx, by;
    xcd_swz(bx, by);
    const int bm = by * 128;
    const int bn = bx * 128;

    const int srow = w * 32 + (lane >> 2);
    const int scol = ((lane & 3) ^ ((lane >> 3) & 3)) * 8;
    const u16* Ag = A + (size_t)(bm + srow) * K + scol;
    const u16* Bg = B + (size_t)(bn + srow) * K + scol;
    u16* AsW = &As[(w * 32) * 32];
    u16* BsW = &Bs[(w * 32) * 32];

    const int mBase = (w >> 1) * 64;
    const int nBase = (w & 1) * 64;
    const int co = ((lane >> 4) ^ (((lane & 15) >> 1) & 3)) * 8;

    f32x4 acc[4][4];
    const f32x4 z4 = {0.f, 0.f, 0.f, 0.f};
#pragma unroll
    for (int a = 0; a < 4; ++a)
#pragma unroll
        for (int b = 0; b < 4; ++b) acc[a][b] = z4;

    auto STAGE = [&](int k0, int b) {
        const int o = b << 12;
        gld16(Ag + k0, AsW + o);
        gld16(Ag + k0 + (size_t)16 * K, AsW + o + 16 * 32);
        gld16(Bg + k0, BsW + o);
        gld16(Bg + k0 + (size_t)16 * K, BsW + o + 16 * 32);
    };
    auto COMPUTE = [&](int b) {
        const int o = b << 12;
        v8bf af[4], bv[4];
#pragma unroll
        for (int t = 0; t < 4; ++t) {
            af[t] = *(const v8bf*)&As[o + (mBase + t * 16 + (lane & 15)) * 32 + co];
            bv[t] = *(const v8bf*)&Bs[o + (nBase + t * 16 + (lane & 15)) * 32 + co];
        }
#pragma unroll
        for (int tm = 0; tm < 4; ++tm)
#pragma unroll
            for (int tn = 0; tn < 4; ++tn)
                acc[tm][tn] = __builtin_amdgcn_mfma_f32_16x16x32_bf16(af[tm], bv[tn], acc[tm][tn], 0, 0, 0);
    };

    const int nt = K >> 5;
    STAGE(0, 0);
    int cur = 0;
    for (int t = 0; t < nt - 1; ++t) {
        STAGE((t + 1) << 5, cur ^ 1);
        asm volatile("s_waitcnt vmcnt(4)" ::: "memory");
        __builtin_amdgcn_s_barrier();
        COMPUTE(cur);
        asm volatile("s_waitcnt lgkmcnt(0)" ::: "memory");
        __builtin_amdgcn_s_barrier();
        cur ^= 1;
    }
    asm volatile("s_waitcnt vmcnt(0)" ::: "memory");
    __builtin_amdgcn_s_barrier();
    COMPUTE(cur);

#pragma unroll
    for (int tm = 0; tm < 4; ++tm) {
        const int r0 = bm + mBase + tm * 16 + (lane >> 4) * 4;
#pragma unroll
        for (int tn = 0; tn < 4; ++tn) {
            const int c = bn + nBase + tn * 16 + (lane & 15);
            if (MODE == 0 && c >= Nreal) continue;
            const float bvv = bias[c];
#pragma unroll
            for (int r = 0; r < 4; ++r) {
                float v = acc[tm][tn][r] + bvv;
                if (MODE == 1) v = (v >= 0.f) ? v : 0.2f * v;
                const size_t o = (size_t)(r0 + r) * ldc + c;
                if (MODE == 0)
                    ((float*)Cout)[o] = v;
                else
                    ((u16*)Cout)[o] = f2b(v);
            }
        }
    }

    // folded loss reduction (one physical block; lossPart written by vq2, a prior
    // dispatch in-stream -> globally visible)
    if (MODE == 0 && blockIdx.x == 0 && blockIdx.y == 0) {
        __shared__ float ls2[4];
        const int wv = threadIdx.x >> 6;
        float s = 0.f;
        for (int i = threadIdx.x; i < BATCH / 4; i += 256) s += lossPart[i];
        for (int off = 32; off > 0; off >>= 1) s += __shfl_down(s, off);
        if ((threadIdx.x & 63) == 0) ls2[wv] = s;
        __syncthreads();
        if (threadIdx.x == 0)
            outLoss[0] = 1.25f * (ls2[0] + ls2[1] + ls2[2] + ls2[3]) / (float)(BATCH * LATENT);
    }
}

// ---------------- VQ finish: reduce 16 partials/row, gather, loss partials; wave per row --------
__global__ __launch_bounds__(256) void vq2(
    const u64* __restrict__ Part, const float* __restrict__ embF,
    const f16* __restrict__ zh, const f16* __restrict__ zl,
    u16* __restrict__ qb, float* __restrict__ lossPart) {
    __shared__ float ls[4];
    const int lane = threadIdx.x & 63;
    const int wv = threadIdx.x >> 6;
    const int row = blockIdx.x * 4 + wv;

    u64 key = (lane < 16) ? Part[(size_t)row * 16 + lane] : ~0ull;
#pragma unroll
    for (int m = 1; m < 16; m <<= 1) {
        u64 o = __shfl_xor((unsigned long long)key, m);
        key = (o < key) ? o : key;
    }
    const int bidx = (int)(__shfl((unsigned long long)key, 0) & 1023ull);

    const float4 q0 = ((const float4*)(embF + (size_t)bidx * LATENT))[2 * lane];
    const float4 q1 = ((const float4*)(embF + (size_t)bidx * LATENT))[2 * lane + 1];
    float qf[8] = {q0.x, q0.y, q0.z, q0.w, q1.x, q1.y, q1.z, q1.w};
    u16 qpack[8];
#pragma unroll
    for (int t = 0; t < 8; ++t) qpack[t] = f2b(qf[t]);
    *(uint4*)(qb + (size_t)row * LATENT + lane * 8) = *(const uint4*)qpack;

    v8hf zh8 = *(const v8hf*)(zh + (size_t)row * LATENT + lane * 8);
    v8hf zl8 = *(const v8hf*)(zl + (size_t)row * LATENT + lane * 8);
    float s = 0.f;
#pragma unroll
    for (int t = 0; t < 8; ++t) {
        float z = ((float)zh8[t] + (float)zl8[t]) * (1.0f / SA);
        float df = qf[t] - z;
        s += df * df;
    }
    for (int off = 32; off > 0; off >>= 1) s += __shfl_down(s, off);
    if (lane == 0) ls[wv] = s;
    __syncthreads();
    if (threadIdx.x == 0) lossPart[blockIdx.x] = ls[0] + ls[1] + ls[2] + ls[3];
}

// ---------------- launch ----------------
extern "C" void kernel_launch(void* const* d_in, const int* in_sizes, int n_in,
                              void* d_out, int out_size, void* d_ws, size_t ws_size,
                              hipStream_t stream) {
    const float* x = (const float*)d_in[0];
    const float* W1 = (const float*)d_in[1];
    const float* b1 = (const float*)d_in[2];
    const float* W2 = (const float*)d_in[3];
    const float* b2 = (const float*)d_in[4];
    const float* emb = (const float*)d_in[5];
    const float* W3 = (const float*)d_in[6];
    const float* b3 = (const float*)d_in[7];
    const float* W4 = (const float*)d_in[8];
    const float* b4 = (const float*)d_in[9];
    float* out = (float*)d_out;

    char* ws = (char*)d_ws;
    size_t off = 0;
    auto alloc = [&](size_t bytes) {
        void* p = ws + off;
        off += (bytes + 255) & ~(size_t)255;
        return p;
    };
    char* A = (char*)alloc((size_t)BATCH * H_ENC * 2);
    char* Breg = (char*)alloc((size_t)BATCH * H_ENC * 2);
    char* C = (char*)alloc((size_t)BATCH * IN_PAD * 2 * 2);
    u16* qb = (u16*)alloc((size_t)BATCH * LATENT * 2);
    u64* Part = (u64*)alloc((size_t)BATCH * 16 * 8);
    float* lossPart = (float*)alloc((BATCH / 4) * 4);
    f16* W1Th = (f16*)alloc((size_t)H_ENC * IN_PAD * 2);
    f16* W1Tl = (f16*)alloc((size_t)H_ENC * IN_PAD * 2);
    f16* W2Th = (f16*)alloc((size_t)LATENT * H_ENC * 2);
    f16* W2Tl = (f16*)alloc((size_t)LATENT * H_ENC * 2);
    f16* eTh = (f16*)alloc((size_t)NUM_EMB * LATENT * 2);
    f16* eTl = (f16*)alloc((size_t)NUM_EMB * LATENT * 2);
    float* eTf = (float*)alloc((size_t)NUM_EMB * LATENT * 4);
    u16* W3T = (u16*)alloc((size_t)H_DEC * LATENT * 2);
    u16* W4T = (u16*)alloc((size_t)OUT_PAD * H_DEC * 2);
    float* enorm = (float*)alloc(NUM_EMB * 4);

    f16* h_hi = (f16*)A;
    f16* h_lo = (f16*)Breg;
    u16* h2 = (u16*)Breg;
    f16* xh = (f16*)C;
    f16* xl = xh + (size_t)BATCH * IN_PAD;
    f16* zh = (f16*)C;
    f16* zl = zh + (size_t)BATCH * LATENT;

    // single merged prep dispatch
    prep<<<50564, 256, 0, stream>>>(x, W1, W2, emb, W3, W4, xh, xl,
                                    W1Th, W1Tl, W2Th, W2Tl, eTh, eTl, eTf, W3T, W4T, enorm);

    // encoder layer 1: 256^2, 32x32x16 MFMA (K=704, 512 WGs)
    gemm2w<1><<<dim3(H_ENC / 256, BATCH / 256), 512, 0, stream>>>(xh, xl, W1Th, W1Tl, b1, h_hi, h_lo, nullptr, H_ENC, IN_PAD);
    // encoder layer 2: 128^2
    gemm2<2><<<dim3(LATENT / 128, BATCH / 128), 256, 0, stream>>>(h_hi, h_lo, W2Th, W2Tl, b2, zh, zl, nullptr, LATENT, H_ENC);
    // distance pass: 128^2, argmin epilogue
    gemm2<3><<<dim3(NUM_EMB / 128, BATCH / 128), 256, 0, stream>>>(zh, zl, eTh, eTl, enorm, nullptr, nullptr, Part, NUM_EMB, LATENT);
    // VQ finish
    vq2<<<BATCH / 4, 256, 0, stream>>>(Part, eTf, zh, zl, qb, lossPart);
    // decoder (bf16, 128^2); last GEMM folds the loss reduction
    gemm_bt<1><<<dim3(H_DEC / 128, BATCH / 128), 256, 0, stream>>>(qb, W3T, b3, h2, H_DEC, LATENT, H_DEC, H_DEC, nullptr, nullptr);
    gemm_bt<0><<<dim3(OUT_PAD / 128, BATCH / 128), 256, 0, stream>>>(h2, W4T, b4, out, OUT_PAD, H_DEC, OUT_DIM, OUT_DIM, lossPart, out + (size_t)BATCH * OUT_DIM);

    (void)in_sizes; (void)n_in; (void)out_size; (void)ws_size;
}